// Round 1
// baseline (6651.984 us; speedup 1.0000x reference)
//
#include <hip/hip_runtime.h>

// GRU scan: T=1024, B=256, D=256.
// Plan: pack weights to bf16 MFMA fragments; big input GEMM xp = x@Wi+bi (bf16, MFMA);
// recurrence: 16 WGs x 16 batch rows, full T scan per WG, h fp32 in LDS (bf16 only as
// MFMA A operand), Wh streamed from L2 as pre-packed fragments.

typedef __attribute__((ext_vector_type(8))) short short8;
typedef __attribute__((ext_vector_type(4))) float f32x4;

#define T_DIM 1024
#define B_DIM 256
#define D_DIM 256

__device__ __forceinline__ unsigned short f2bf(float f) {
  union { float f; unsigned u; } c; c.f = f;
  unsigned r = c.u + 0x7FFFu + ((c.u >> 16) & 1u);  // RNE
  return (unsigned short)(r >> 16);
}
__device__ __forceinline__ float bf2f(unsigned v16) {
  union { unsigned u; float f; } c; c.u = v16 << 16;
  return c.f;
}
__device__ __forceinline__ float sigm(float x) {
  return 1.0f / (1.0f + __expf(-x));
}
__device__ __forceinline__ float tanh_(float x) {
  float xc = fminf(fmaxf(x, -30.f), 30.f);
  float e = __expf(-2.0f * xc);
  return (1.0f - e) / (1.0f + e);
}

// resets dtype is ambiguous (reference dtype is bool). Classify the buffer on device:
// flags[0]=1 -> float32 (saw 0x3F800000), flags[1]=1 -> packed bytes (saw value not in {0,1}).
__global__ void detect_resets(const int* __restrict__ r, int n, int* __restrict__ flags) {
  int isf = 0, oth = 0;
  for (int i = blockIdx.x * blockDim.x + threadIdx.x; i < n; i += gridDim.x * blockDim.x) {
    int v = r[i];
    if (v == 0x3F800000) isf = 1;
    else if (v != 0 && v != 1) oth = 1;
  }
  if (isf) atomicOr(&flags[0], 1);
  if (oth) atomicOr(&flags[1], 1);
}

__device__ __forceinline__ int read_reset(const void* r, int f0, int f1, int idx) {
  if (f0) return ((const float*)r)[idx] != 0.0f;
  if (f1) return ((const unsigned char*)r)[idx] != 0;
  return ((const int*)r)[idx] != 0;
}

// Pack WiT (768x256 bf16, transposed Wi) and Wpk (48 ntiles x 8 ksteps x 64 lanes x 8 bf16
// fragment layout of [Whr|Whz|Whn] as the B-operand of mfma_f32_16x16x32_bf16).
__global__ void pack_weights(const float* __restrict__ Wi,
                             const float* __restrict__ Whr,
                             const float* __restrict__ Whz,
                             const float* __restrict__ Whn,
                             unsigned short* __restrict__ WiT,
                             unsigned short* __restrict__ Wpk) {
  int gid = blockIdx.x * 256 + threadIdx.x;
  const int NE = 768 * 256;
  if (gid < NE) {
    int n = gid >> 8, k = gid & 255;
    WiT[gid] = f2bf(Wi[k * 768 + n]);
  } else if (gid < 2 * NE) {
    int g = gid - NE;
    int j = g & 7, l = (g >> 3) & 63, ks = (g >> 9) & 7, nt = g >> 12;
    int k = ks * 32 + (l >> 4) * 8 + j;       // B-frag: row k = kstep*32 + 8*(lane>>4)+j
    int col = nt * 16 + (l & 15);             //         col = ntile*16 + (lane&15)
    float w;
    if (col < 256)      w = Whr[k * 256 + col];
    else if (col < 512) w = Whz[k * 256 + col - 256];
    else                w = Whn[k * 256 + col - 512];
    Wpk[g] = f2bf(w);
  }
}

// xp[m][n] = sum_k x[m][k]*Wi[k][n] + bi[n], output bf16. 128x128 tile, BK=64, 4 waves 2x2.
// grid = (6 N-blocks, Mc/128 M-blocks): N fastest so x is HBM-read once.
__global__ __launch_bounds__(256) void gemm_xp(
    const float* __restrict__ x, const unsigned short* __restrict__ WiT,
    const float* __restrict__ bi, unsigned short* __restrict__ xp) {
  __shared__ __align__(16) unsigned short Al[128 * 64];  // XOR-swizzled bf16
  __shared__ __align__(16) unsigned short Bl[128 * 64];  // rows = n, cols = k (WiT layout)
  const int tid = threadIdx.x;
  const int l = tid & 63, wid = tid >> 6;
  const int wm = wid >> 1, wn = wid & 1;
  const int n0 = blockIdx.x * 128;
  const long m0 = (long)blockIdx.y * 128;
  f32x4 acc[4][4] = {};
  for (int kb = 0; kb < 4; ++kb) {
    const int k0 = kb * 64;
    if (kb) __syncthreads();
#pragma unroll
    for (int i = 0; i < 8; ++i) {  // stage A: fp32 -> bf16
      int fidx = i * 256 + tid;
      int row = fidx >> 4, kf = fidx & 15;
      float4 v = *(const float4*)&x[(m0 + row) * 256 + k0 + kf * 4];
      uint2 p;
      p.x = f2bf(v.x) | ((unsigned)f2bf(v.y) << 16);
      p.y = f2bf(v.z) | ((unsigned)f2bf(v.w) << 16);
      int byte = (row * 128 + kf * 8) ^ ((row & 7) << 4);
      *(uint2*)((char*)Al + byte) = p;
    }
#pragma unroll
    for (int i = 0; i < 4; ++i) {  // stage B (already bf16, transposed)
      int cidx = i * 256 + tid;
      int row = cidx >> 3, kc = cidx & 7;
      short8 v = *(const short8*)&WiT[(n0 + row) * 256 + k0 + kc * 8];
      int byte = (row * 128 + kc * 16) ^ ((row & 7) << 4);
      *(short8*)((char*)Bl + byte) = v;
    }
    __syncthreads();
#pragma unroll
    for (int kk = 0; kk < 2; ++kk) {
      short8 af[4], bfv[4];
#pragma unroll
      for (int t = 0; t < 4; ++t) {
        int m = wm * 64 + t * 16 + (l & 15);
        af[t] = *(const short8*)((char*)Al + ((m * 128 + kk * 64 + (l >> 4) * 16) ^ ((m & 7) << 4)));
        int n = wn * 64 + t * 16 + (l & 15);
        bfv[t] = *(const short8*)((char*)Bl + ((n * 128 + kk * 64 + (l >> 4) * 16) ^ ((n & 7) << 4)));
      }
#pragma unroll
      for (int tm = 0; tm < 4; ++tm)
#pragma unroll
        for (int tn = 0; tn < 4; ++tn)
          acc[tm][tn] = __builtin_amdgcn_mfma_f32_16x16x32_bf16(af[tm], bfv[tn], acc[tm][tn], 0, 0, 0);
    }
  }
#pragma unroll
  for (int tn = 0; tn < 4; ++tn) {
    int n = n0 + wn * 64 + tn * 16 + (l & 15);
    float bv = bi[n];
#pragma unroll
    for (int tm = 0; tm < 4; ++tm) {
#pragma unroll
      for (int r = 0; r < 4; ++r) {
        long m = m0 + wm * 64 + tm * 16 + (l >> 4) * 4 + r;  // C/D: col=lane&15, row=(lane>>4)*4+r
        xp[m * 768 + n] = f2bf(acc[tm][tn][r] + bv);
      }
    }
  }
}

// Recurrent scan. 16 WGs, each owns 16 batch rows for the whole chunk.
// Per step: mm = h16 @ Wpk (16x256 @ 256x768 via MFMA, N split over 8 waves),
// barrier, gate math fp32 (h carried fp32 in LDS), barrier.
__global__ __launch_bounds__(512) void rnn_scan(
    const unsigned short* __restrict__ xp, const void* __restrict__ resets,
    const float* __restrict__ bhn, const unsigned short* __restrict__ Wpk,
    const int* __restrict__ flags, float* __restrict__ y,
    float* __restrict__ hws, int t0, int Tc) {
  __shared__ __align__(16) unsigned short hb16[16 * 256];  // XOR-swizzled bf16 h (MFMA A)
  __shared__ float h32[16 * 256];                          // fp32 h (gate math carry)
  __shared__ float mm[16 * 772];                           // step GEMM result (+4 pad)
  const int tid = threadIdx.x;
  const int l = tid & 63, wid = tid >> 6;
  const int B0 = blockIdx.x * 16;
  const int f0 = flags[0], f1 = flags[1];

#pragma unroll
  for (int i = 0; i < 4; ++i) {  // init h (chunk start)
    int e = i * 512 + tid;
    int b = e >> 7, d = (e & 127) * 2;
    float2 hv; hv.x = 0.f; hv.y = 0.f;
    if (t0 > 0) {
      hv = *(const float2*)&hws[(B0 + b) * 256 + d];
      if (read_reset(resets, f0, f1, t0 * 256 + B0 + b)) { hv.x = 0.f; hv.y = 0.f; }
    }
    *(float2*)&h32[b * 256 + d] = hv;
    unsigned hp = f2bf(hv.x) | ((unsigned)f2bf(hv.y) << 16);
    *(unsigned*)((char*)hb16 + ((b * 512 + d * 2) ^ ((b & 7) << 4))) = hp;
  }
  __syncthreads();

  const int nt0 = wid * 6;  // 6 ntiles (96 cols) per wave
  for (int ts = 0; ts < Tc; ++ts) {
    const int tg = t0 + ts;
    f32x4 acc[6] = {};
    short8 afr[8];
#pragma unroll
    for (int kk = 0; kk < 8; ++kk)  // all A-frags up front (conflict-free via swizzle)
      afr[kk] = *(const short8*)((char*)hb16 +
          (((l & 15) * 512 + kk * 64 + (l >> 4) * 16) ^ ((l & 7) << 4)));
    short8 bfr[3][6];  // 2-deep L2 prefetch of weight fragments
#pragma unroll
    for (int j = 0; j < 6; ++j) {
      bfr[0][j] = *(const short8*)&Wpk[(((nt0 + j) * 8 + 0) * 64 + l) * 8];
      bfr[1][j] = *(const short8*)&Wpk[(((nt0 + j) * 8 + 1) * 64 + l) * 8];
    }
#pragma unroll
    for (int kk = 0; kk < 8; ++kk) {
      const int cur = kk % 3;
      if (kk + 2 < 8) {
        const int nxt = (kk + 2) % 3;
#pragma unroll
        for (int j = 0; j < 6; ++j)
          bfr[nxt][j] = *(const short8*)&Wpk[(((nt0 + j) * 8 + kk + 2) * 64 + l) * 8];
      }
#pragma unroll
      for (int j = 0; j < 6; ++j)
        acc[j] = __builtin_amdgcn_mfma_f32_16x16x32_bf16(afr[kk], bfr[cur][j], acc[j], 0, 0, 0);
    }
#pragma unroll
    for (int j = 0; j < 6; ++j) {
      const int col = wid * 96 + j * 16 + (l & 15);
      const int rw = (l >> 4) * 4;
#pragma unroll
      for (int r = 0; r < 4; ++r) mm[(rw + r) * 772 + col] = acc[j][r];
    }
    __syncthreads();
#pragma unroll
    for (int i = 0; i < 4; ++i) {  // gate phase: 2 adjacent d per thread
      int e = i * 512 + tid;
      int b = e >> 7, d = (e & 127) * 2;
      float2 mr = *(const float2*)&mm[b * 772 + d];
      float2 mz = *(const float2*)&mm[b * 772 + 256 + d];
      float2 mn = *(const float2*)&mm[b * 772 + 512 + d];
      const unsigned short* xr_p = xp + ((long)ts * 256 + B0 + b) * 768;
      unsigned xr = *(const unsigned*)(xr_p + d);
      unsigned xz = *(const unsigned*)(xr_p + 256 + d);
      unsigned xn = *(const unsigned*)(xr_p + 512 + d);
      float2 h = *(const float2*)&h32[b * 256 + d];
      float r0 = sigm(bf2f(xr & 0xffffu) + mr.x);
      float r1 = sigm(bf2f(xr >> 16) + mr.y);
      float z0 = sigm(bf2f(xz & 0xffffu) + mz.x);
      float z1 = sigm(bf2f(xz >> 16) + mz.y);
      float n0 = tanh_(bf2f(xn & 0xffffu) + r0 * (mn.x + bhn[d]));
      float n1 = tanh_(bf2f(xn >> 16) + r1 * (mn.y + bhn[d + 1]));
      float2 out;
      out.x = (1.f - z0) * n0 + z0 * h.x;
      out.y = (1.f - z1) * n1 + z1 * h.y;
      *(float2*)&y[((long)tg * 256 + B0 + b) * 256 + d] = out;
      // apply NEXT step's reset mask when storing the carry
      int rst = (tg + 1 < T_DIM) ? read_reset(resets, f0, f1, (tg + 1) * 256 + B0 + b) : 0;
      float2 hw = out;
      if (rst) { hw.x = 0.f; hw.y = 0.f; }
      *(float2*)&h32[b * 256 + d] = hw;
      unsigned hp = f2bf(hw.x) | ((unsigned)f2bf(hw.y) << 16);
      *(unsigned*)((char*)hb16 + ((b * 512 + d * 2) ^ ((b & 7) << 4))) = hp;
    }
    __syncthreads();
  }
#pragma unroll
  for (int i = 0; i < 4; ++i) {  // save carry for next chunk
    int e = i * 512 + tid;
    int b = e >> 7, d = (e & 127) * 2;
    *(float2*)&hws[(B0 + b) * 256 + d] = *(const float2*)&h32[b * 256 + d];
  }
}

extern "C" void kernel_launch(void* const* d_in, const int* in_sizes, int n_in,
                              void* d_out, int out_size, void* d_ws, size_t ws_size,
                              hipStream_t stream) {
  const float* x    = (const float*)d_in[0];
  const void*  rst  = d_in[1];
  const float* Wi   = (const float*)d_in[2];
  const float* bi   = (const float*)d_in[3];
  const float* Whr  = (const float*)d_in[4];
  const float* Whz  = (const float*)d_in[5];
  const float* Whn  = (const float*)d_in[6];
  const float* bhn  = (const float*)d_in[7];
  float* y = (float*)d_out;

  char* ws = (char*)d_ws;
  unsigned short* Wpk = (unsigned short*)(ws);             // 393216 B
  unsigned short* WiT = (unsigned short*)(ws + 393216);    // 393216 B
  float* hws          = (float*)(ws + 786432);             // 262144 B
  int* flags          = (int*)(ws + 1048576);              // 8 B (+pad)
  unsigned short* xpb = (unsigned short*)(ws + 1048576 + 256);

  const size_t fixed = 1048576 + 256;
  int Tc = T_DIM;
  while (Tc > 1 && fixed + (size_t)Tc * B_DIM * 768 * 2 > ws_size) Tc >>= 1;

  hipMemsetAsync(flags, 0, 8, stream);
  detect_resets<<<64, 256, 0, stream>>>((const int*)rst, T_DIM * B_DIM / 4, flags);
  pack_weights<<<1536, 256, 0, stream>>>(Wi, Whr, Whz, Whn, WiT, Wpk);
  for (int t0 = 0; t0 < T_DIM; t0 += Tc) {
    gemm_xp<<<dim3(6, Tc * 2), 256, 0, stream>>>(x + (long)t0 * B_DIM * D_DIM, WiT, bi, xpb);
    rnn_scan<<<16, 512, 0, stream>>>(xpb, rst, bhn, Wpk, flags, y, hws, t0, Tc);
  }
}

// Round 2
// 3329.385 us; speedup vs baseline: 1.9980x; 1.9980x over previous
//
#include <hip/hip_runtime.h>

// GRU scan: T=1024, B=256, D=256.
// rnn_scan v2: weights register/LDS-resident (no per-step L2 refetch), swapped MFMA
// operands (D: col=batch, row=4 consecutive d) so gates run fully in registers,
// h carried in regs, 1 raw barrier/step (lgkmcnt only -> xp prefetch survives barrier).

typedef __attribute__((ext_vector_type(8))) short short8;
typedef __attribute__((ext_vector_type(4))) float f32x4;

#define T_DIM 1024
#define B_DIM 256
#define D_DIM 256

__device__ __forceinline__ unsigned short f2bf(float f) {
  union { float f; unsigned u; } c; c.f = f;
  unsigned r = c.u + 0x7FFFu + ((c.u >> 16) & 1u);  // RNE
  return (unsigned short)(r >> 16);
}
__device__ __forceinline__ float bf2f(unsigned v16) {
  union { unsigned u; float f; } c; c.u = v16 << 16;
  return c.f;
}
__device__ __forceinline__ float sigm(float x) {
  return __fdividef(1.0f, 1.0f + __expf(-x));
}
__device__ __forceinline__ float tanh_(float x) {
  float xc = fminf(fmaxf(x, -15.f), 15.f);
  float e = __expf(-2.0f * xc);
  return __fdividef(1.0f - e, 1.0f + e);
}
__device__ __forceinline__ float bfx(uint2 v, int r) {
  unsigned w = (r & 2) ? v.y : v.x;
  unsigned h = (r & 1) ? (w >> 16) : (w & 0xffffu);
  return bf2f(h);
}

// resets dtype ambiguous (reference dtype bool). flags[0]=float32, flags[1]=bytes.
__global__ void detect_resets(const int* __restrict__ r, int n, int* __restrict__ flags) {
  int isf = 0, oth = 0;
  for (int i = blockIdx.x * blockDim.x + threadIdx.x; i < n; i += gridDim.x * blockDim.x) {
    int v = r[i];
    if (v == 0x3F800000) isf = 1;
    else if (v != 0 && v != 1) oth = 1;
  }
  if (isf) atomicOr(&flags[0], 1);
  if (oth) atomicOr(&flags[1], 1);
}

__device__ __forceinline__ int read_reset(const void* r, int f0, int f1, int idx) {
  if (f0) return ((const float*)r)[idx] != 0.0f;
  if (f1) return ((const unsigned char*)r)[idx] != 0;
  return ((const int*)r)[idx] != 0;
}

// One-time: normalize resets to bytes so the hot loop has no dtype branches.
__global__ void convert_resets(const void* __restrict__ rst, const int* __restrict__ flags,
                               unsigned char* __restrict__ rst8) {
  int f0 = flags[0], f1 = flags[1];
  for (int i = blockIdx.x * blockDim.x + threadIdx.x; i < T_DIM * B_DIM;
       i += gridDim.x * blockDim.x)
    rst8[i] = (unsigned char)read_reset(rst, f0, f1, i);
}

// Pack WiT (768x256 bf16, transposed Wi) and Wpk: frag(dt,ks) element (l,j) =
// W[ks*32 + (l>>4)*8 + j][dt*16 + (l&15)] — serves as A-operand (row=l&15=d-sub).
__global__ void pack_weights(const float* __restrict__ Wi,
                             const float* __restrict__ Whr,
                             const float* __restrict__ Whz,
                             const float* __restrict__ Whn,
                             unsigned short* __restrict__ WiT,
                             unsigned short* __restrict__ Wpk) {
  int gid = blockIdx.x * 256 + threadIdx.x;
  const int NE = 768 * 256;
  if (gid < NE) {
    int n = gid >> 8, k = gid & 255;
    WiT[gid] = f2bf(Wi[k * 768 + n]);
  } else if (gid < 2 * NE) {
    int g = gid - NE;
    int j = g & 7, l = (g >> 3) & 63, ks = (g >> 9) & 7, nt = g >> 12;
    int k = ks * 32 + (l >> 4) * 8 + j;
    int col = nt * 16 + (l & 15);
    float w;
    if (col < 256)      w = Whr[k * 256 + col];
    else if (col < 512) w = Whz[k * 256 + col - 256];
    else                w = Whn[k * 256 + col - 512];
    Wpk[g] = f2bf(w);
  }
}

// xp[m][n] = x@Wi + bi, output bf16 in [T*B][768] layout. (unchanged from r1)
__global__ __launch_bounds__(256) void gemm_xp(
    const float* __restrict__ x, const unsigned short* __restrict__ WiT,
    const float* __restrict__ bi, unsigned short* __restrict__ xp) {
  __shared__ __align__(16) unsigned short Al[128 * 64];
  __shared__ __align__(16) unsigned short Bl[128 * 64];
  const int tid = threadIdx.x;
  const int l = tid & 63, wid = tid >> 6;
  const int wm = wid >> 1, wn = wid & 1;
  const int n0 = blockIdx.x * 128;
  const long m0 = (long)blockIdx.y * 128;
  f32x4 acc[4][4] = {};
  for (int kb = 0; kb < 4; ++kb) {
    const int k0 = kb * 64;
    if (kb) __syncthreads();
#pragma unroll
    for (int i = 0; i < 8; ++i) {
      int fidx = i * 256 + tid;
      int row = fidx >> 4, kf = fidx & 15;
      float4 v = *(const float4*)&x[(m0 + row) * 256 + k0 + kf * 4];
      uint2 p;
      p.x = f2bf(v.x) | ((unsigned)f2bf(v.y) << 16);
      p.y = f2bf(v.z) | ((unsigned)f2bf(v.w) << 16);
      int byte = (row * 128 + kf * 8) ^ ((row & 7) << 4);
      *(uint2*)((char*)Al + byte) = p;
    }
#pragma unroll
    for (int i = 0; i < 4; ++i) {
      int cidx = i * 256 + tid;
      int row = cidx >> 3, kc = cidx & 7;
      short8 v = *(const short8*)&WiT[(n0 + row) * 256 + k0 + kc * 8];
      int byte = (row * 128 + kc * 16) ^ ((row & 7) << 4);
      *(short8*)((char*)Bl + byte) = v;
    }
    __syncthreads();
#pragma unroll
    for (int kk = 0; kk < 2; ++kk) {
      short8 af[4], bfv[4];
#pragma unroll
      for (int t = 0; t < 4; ++t) {
        int m = wm * 64 + t * 16 + (l & 15);
        af[t] = *(const short8*)((char*)Al + ((m * 128 + kk * 64 + (l >> 4) * 16) ^ ((m & 7) << 4)));
        int n = wn * 64 + t * 16 + (l & 15);
        bfv[t] = *(const short8*)((char*)Bl + ((n * 128 + kk * 64 + (l >> 4) * 16) ^ ((n & 7) << 4)));
      }
#pragma unroll
      for (int tm = 0; tm < 4; ++tm)
#pragma unroll
        for (int tn = 0; tn < 4; ++tn)
          acc[tm][tn] = __builtin_amdgcn_mfma_f32_16x16x32_bf16(af[tm], bfv[tn], acc[tm][tn], 0, 0, 0);
    }
  }
#pragma unroll
  for (int tn = 0; tn < 4; ++tn) {
    int n = n0 + wn * 64 + tn * 16 + (l & 15);
    float bv = bi[n];
#pragma unroll
    for (int tm = 0; tm < 4; ++tm) {
#pragma unroll
      for (int r = 0; r < 4; ++r) {
        long m = m0 + wm * 64 + tm * 16 + (l >> 4) * 4 + r;
        xp[m * 768 + n] = f2bf(acc[tm][tn][r] + bv);
      }
    }
  }
}

// Recurrent scan v2. 16 WGs x 512 threads (8 waves). Wave wid owns output cols
// d in [wid*32, wid*32+32) for each gate. Tiles (dt): r: wid*2,wid*2+1 (regs);
// z: 16+wid*2,+1 (regs); n: 32+wid*2,+1 (LDS). acc = mfma(Wfrag, hfrag):
// D col = batch = l&15, D row = grp*4+r = d-sub -> lane owns 4 consecutive d per tile.
__global__ __launch_bounds__(512, 2) void rnn_scan(
    const unsigned short* __restrict__ xp, const unsigned char* __restrict__ rst8,
    const float* __restrict__ bhn, const unsigned short* __restrict__ Wpk,
    float* __restrict__ y, float* __restrict__ hws, int t0, int Tc) {
  __shared__ __align__(16) unsigned short hb16[2][16 * 256];   // 16 KB dbuf, XOR-swz
  __shared__ __align__(16) unsigned short wlds[8 * 16 * 512];  // 128 KB: 16 frags/wave
  const int tid = threadIdx.x;
  const int l = tid & 63, wid = tid >> 6;
  const int b = l & 15, grp = l >> 4;
  const int B0 = blockIdx.x * 16;
  const int sw = (b & 7) << 4;
  const int d0_0 = wid * 32 + grp * 4;
  const int d0_1 = d0_0 + 16;

  // ---- stage LDS weights: n-gate tiles (dt = 32+wid*2, 33+wid*2), 16 frags ----
#pragma unroll
  for (int f = 0; f < 16; ++f) {
    int dt = 32 + wid * 2 + (f >> 3);
    int kk = f & 7;
    short8 v = *(const short8*)&Wpk[((dt * 8 + kk) * 64 + l) * 8];
    *(short8*)&wlds[((wid * 16 + f) * 64 + l) * 8] = v;
  }
  // ---- register weights: r,z tiles (4 tiles x 8 ksteps = 32 frags = 128 VGPR) ----
  short8 wreg[32];
#pragma unroll
  for (int t = 0; t < 4; ++t) {
    int dt = (t < 2) ? (wid * 2 + t) : (16 + wid * 2 + (t - 2));
#pragma unroll
    for (int kk = 0; kk < 8; ++kk)
      wreg[t * 8 + kk] = *(const short8*)&Wpk[((dt * 8 + kk) * 64 + l) * 8];
  }
  float4 bh0 = *(const float4*)&bhn[d0_0];
  float4 bh1 = *(const float4*)&bhn[d0_1];

  // ---- init h (registers) + hb16[0] ----
  float4 h0 = {0.f, 0.f, 0.f, 0.f}, h1 = {0.f, 0.f, 0.f, 0.f};
  if (t0 > 0) {
    h0 = *(const float4*)&hws[(B0 + b) * 256 + d0_0];
    h1 = *(const float4*)&hws[(B0 + b) * 256 + d0_1];
    if (rst8[t0 * 256 + B0 + b]) { h0 = {0.f,0.f,0.f,0.f}; h1 = {0.f,0.f,0.f,0.f}; }
  }
  {
    uint2 p0, p1;
    p0.x = f2bf(h0.x) | ((unsigned)f2bf(h0.y) << 16);
    p0.y = f2bf(h0.z) | ((unsigned)f2bf(h0.w) << 16);
    p1.x = f2bf(h1.x) | ((unsigned)f2bf(h1.y) << 16);
    p1.y = f2bf(h1.z) | ((unsigned)f2bf(h1.w) << 16);
    *(uint2*)((char*)&hb16[0][0] + ((b * 512 + d0_0 * 2) ^ sw)) = p0;
    *(uint2*)((char*)&hb16[0][0] + ((b * 512 + d0_1 * 2) ^ sw)) = p1;
  }
  __syncthreads();

  // ---- prefetch xp + reset for step 0 ----
  const unsigned short* xrow = xp + ((long)0 * 256 + B0 + b) * 768;
  uint2 xr0 = *(const uint2*)(xrow + d0_0);
  uint2 xr1 = *(const uint2*)(xrow + d0_1);
  uint2 xz0 = *(const uint2*)(xrow + 256 + d0_0);
  uint2 xz1 = *(const uint2*)(xrow + 256 + d0_1);
  uint2 xn0 = *(const uint2*)(xrow + 512 + d0_0);
  uint2 xn1 = *(const uint2*)(xrow + 512 + d0_1);
  int rstn = (t0 + 1 < T_DIM) ? (int)rst8[(t0 + 1) * 256 + B0 + b] : 0;

  for (int ts = 0; ts < Tc; ++ts) {
    const int cur = ts & 1, nxt = cur ^ 1;
    const char* hb = (const char*)&hb16[cur][0];
    const int wb = wid * 16;
    // ring buffers (static %3 indices under full unroll)
    short8 hfr[3], wl4[3], wl5[3];
#define LD_H(k)  (*(const short8*)(hb + ((b * 512 + (k) * 64 + grp * 16) ^ sw)))
#define LD_W4(k) (*(const short8*)&wlds[((wb + (k)) * 64 + l) * 8])
#define LD_W5(k) (*(const short8*)&wlds[((wb + 8 + (k)) * 64 + l) * 8])
    hfr[0] = LD_H(0); wl4[0] = LD_W4(0); wl5[0] = LD_W5(0);
    hfr[1] = LD_H(1); wl4[1] = LD_W4(1); wl5[1] = LD_W5(1);
    f32x4 acc[6] = {};
#pragma unroll
    for (int kk = 0; kk < 8; ++kk) {
      if (kk + 2 < 8) {
        hfr[(kk + 2) % 3] = LD_H(kk + 2);
        wl4[(kk + 2) % 3] = LD_W4(kk + 2);
        wl5[(kk + 2) % 3] = LD_W5(kk + 2);
      }
      const int s = kk % 3;
      acc[0] = __builtin_amdgcn_mfma_f32_16x16x32_bf16(wreg[kk],      hfr[s], acc[0], 0, 0, 0);
      acc[1] = __builtin_amdgcn_mfma_f32_16x16x32_bf16(wreg[8 + kk],  hfr[s], acc[1], 0, 0, 0);
      acc[2] = __builtin_amdgcn_mfma_f32_16x16x32_bf16(wreg[16 + kk], hfr[s], acc[2], 0, 0, 0);
      acc[3] = __builtin_amdgcn_mfma_f32_16x16x32_bf16(wreg[24 + kk], hfr[s], acc[3], 0, 0, 0);
      acc[4] = __builtin_amdgcn_mfma_f32_16x16x32_bf16(wl4[s], hfr[s], acc[4], 0, 0, 0);
      acc[5] = __builtin_amdgcn_mfma_f32_16x16x32_bf16(wl5[s], hfr[s], acc[5], 0, 0, 0);
    }
#undef LD_H
#undef LD_W4
#undef LD_W5
    // ---- gates (all in registers) ----
    const int tg = t0 + ts;
    float4 o0, o1;
#pragma unroll
    for (int r = 0; r < 4; ++r) {
      float rg = sigm(bfx(xr0, r) + acc[0][r]);
      float zg = sigm(bfx(xz0, r) + acc[2][r]);
      float ng = tanh_(bfx(xn0, r) + rg * (acc[4][r] + bh0[r]));
      o0[r] = (1.f - zg) * ng + zg * h0[r];
      rg = sigm(bfx(xr1, r) + acc[1][r]);
      zg = sigm(bfx(xz1, r) + acc[3][r]);
      ng = tanh_(bfx(xn1, r) + rg * (acc[5][r] + bh1[r]));
      o1[r] = (1.f - zg) * ng + zg * h1[r];
    }
    *(float4*)&y[((long)tg * 256 + B0 + b) * 256 + d0_0] = o0;
    *(float4*)&y[((long)tg * 256 + B0 + b) * 256 + d0_1] = o1;
    // carry (mask with next step's reset), write hb16[nxt]
    const float m = rstn ? 0.f : 1.f;
    h0.x = o0.x * m; h0.y = o0.y * m; h0.z = o0.z * m; h0.w = o0.w * m;
    h1.x = o1.x * m; h1.y = o1.y * m; h1.z = o1.z * m; h1.w = o1.w * m;
    {
      uint2 p0, p1;
      p0.x = f2bf(h0.x) | ((unsigned)f2bf(h0.y) << 16);
      p0.y = f2bf(h0.z) | ((unsigned)f2bf(h0.w) << 16);
      p1.x = f2bf(h1.x) | ((unsigned)f2bf(h1.y) << 16);
      p1.y = f2bf(h1.z) | ((unsigned)f2bf(h1.w) << 16);
      *(uint2*)((char*)&hb16[nxt][0] + ((b * 512 + d0_0 * 2) ^ sw)) = p0;
      *(uint2*)((char*)&hb16[nxt][0] + ((b * 512 + d0_1 * 2) ^ sw)) = p1;
    }
    // ---- prefetch next step (stays in flight across the raw barrier) ----
    if (ts + 1 < Tc) {
      const unsigned short* xr_n = xp + ((long)(ts + 1) * 256 + B0 + b) * 768;
      xr0 = *(const uint2*)(xr_n + d0_0);
      xr1 = *(const uint2*)(xr_n + d0_1);
      xz0 = *(const uint2*)(xr_n + 256 + d0_0);
      xz1 = *(const uint2*)(xr_n + 256 + d0_1);
      xn0 = *(const uint2*)(xr_n + 512 + d0_0);
      xn1 = *(const uint2*)(xr_n + 512 + d0_1);
      rstn = (tg + 2 < T_DIM) ? (int)rst8[(tg + 2) * 256 + B0 + b] : 0;
    }
    // raw barrier: drain LDS only (vmcnt NOT drained -> xp prefetch hidden)
    asm volatile("s_waitcnt lgkmcnt(0)" ::: "memory");
    __builtin_amdgcn_s_barrier();
  }
  // save carry for next chunk
  *(float4*)&hws[(B0 + b) * 256 + d0_0] = h0;
  *(float4*)&hws[(B0 + b) * 256 + d0_1] = h1;
}

extern "C" void kernel_launch(void* const* d_in, const int* in_sizes, int n_in,
                              void* d_out, int out_size, void* d_ws, size_t ws_size,
                              hipStream_t stream) {
  const float* x    = (const float*)d_in[0];
  const void*  rst  = d_in[1];
  const float* Wi   = (const float*)d_in[2];
  const float* bi   = (const float*)d_in[3];
  const float* Whr  = (const float*)d_in[4];
  const float* Whz  = (const float*)d_in[5];
  const float* Whn  = (const float*)d_in[6];
  const float* bhn  = (const float*)d_in[7];
  float* y = (float*)d_out;

  char* ws = (char*)d_ws;
  unsigned short* Wpk = (unsigned short*)(ws);              // 393216 B
  unsigned short* WiT = (unsigned short*)(ws + 393216);     // 393216 B
  float* hws          = (float*)(ws + 786432);              // 262144 B
  int* flags          = (int*)(ws + 1048576);               // 256 B slot
  unsigned char* rst8 = (unsigned char*)(ws + 1048832);     // 262144 B
  unsigned short* xpb = (unsigned short*)(ws + 1310976);

  const size_t fixed = 1310976;
  int Tc = T_DIM;
  while (Tc > 1 && fixed + (size_t)Tc * B_DIM * 768 * 2 > ws_size) Tc >>= 1;

  hipMemsetAsync(flags, 0, 8, stream);
  detect_resets<<<64, 256, 0, stream>>>((const int*)rst, T_DIM * B_DIM / 4, flags);
  convert_resets<<<256, 256, 0, stream>>>(rst, flags, rst8);
  pack_weights<<<1536, 256, 0, stream>>>(Wi, Whr, Whz, Whn, WiT, Wpk);
  for (int t0 = 0; t0 < T_DIM; t0 += Tc) {
    gemm_xp<<<dim3(6, Tc * 2), 256, 0, stream>>>(x + (long)t0 * B_DIM * D_DIM, WiT, bi, xpb);
    rnn_scan<<<16, 512, 0, stream>>>(xpb, rst8, bhn, Wpk, y, hws, t0, Tc);
  }
}

// Round 3
// 2926.014 us; speedup vs baseline: 2.2734x; 1.1379x over previous
//
#include <hip/hip_runtime.h>

// GRU scan: T=1024, B=256, D=256.
// rnn_scan v3: 32 WGs x 8 batch rows (batch split buys CUs; MFMA cols 8-15 wasted
// but MFMA is ~1% util). ALL 48 weight frags register-resident (192 VGPR) -> LDS
// traffic = 8 h-frag reads/wave/step only. DPP row_shr:8 redistributes odd-tile
// accumulators so all 64 lanes do 4 gate elements each (no masked-lane waste).

typedef __attribute__((ext_vector_type(8))) short short8;
typedef __attribute__((ext_vector_type(4))) float f32x4;

#define T_DIM 1024
#define B_DIM 256
#define D_DIM 256

__device__ __forceinline__ unsigned short f2bf(float f) {
  union { float f; unsigned u; } c; c.f = f;
  unsigned r = c.u + 0x7FFFu + ((c.u >> 16) & 1u);  // RNE
  return (unsigned short)(r >> 16);
}
__device__ __forceinline__ float bf2f(unsigned v16) {
  union { unsigned u; float f; } c; c.u = v16 << 16;
  return c.f;
}
__device__ __forceinline__ float sigm(float x) {
  return __fdividef(1.0f, 1.0f + __expf(-x));
}
__device__ __forceinline__ float tanh_(float x) {
  float xc = fminf(fmaxf(x, -15.f), 15.f);
  float e = __expf(-2.0f * xc);
  return __fdividef(1.0f - e, 1.0f + e);
}
__device__ __forceinline__ float bfx(uint2 v, int r) {
  unsigned w = (r & 2) ? v.y : v.x;
  unsigned h = (r & 1) ? (w >> 16) : (w & 0xffffu);
  return bf2f(h);
}
// lanes p>=8 (p = lane&15) take `other` from lane p-8; lanes p<8 keep `own`.
// row_shr:8 = 0x118, row_mask 0xF, bank_mask 0xC (banks 2,3 = lanes 8-15 per row).
__device__ __forceinline__ float take_hi(float own, float other) {
  union { float f; int i; } o, s, r;
  o.f = own; s.f = other;
  r.i = __builtin_amdgcn_update_dpp(o.i, s.i, 0x118, 0xF, 0xC, false);
  return r.f;
}

// resets dtype ambiguous (reference dtype bool). flags[0]=float32, flags[1]=bytes.
__global__ void detect_resets(const int* __restrict__ r, int n, int* __restrict__ flags) {
  int isf = 0, oth = 0;
  for (int i = blockIdx.x * blockDim.x + threadIdx.x; i < n; i += gridDim.x * blockDim.x) {
    int v = r[i];
    if (v == 0x3F800000) isf = 1;
    else if (v != 0 && v != 1) oth = 1;
  }
  if (isf) atomicOr(&flags[0], 1);
  if (oth) atomicOr(&flags[1], 1);
}

__device__ __forceinline__ int read_reset(const void* r, int f0, int f1, int idx) {
  if (f0) return ((const float*)r)[idx] != 0.0f;
  if (f1) return ((const unsigned char*)r)[idx] != 0;
  return ((const int*)r)[idx] != 0;
}

__global__ void convert_resets(const void* __restrict__ rst, const int* __restrict__ flags,
                               unsigned char* __restrict__ rst8) {
  int f0 = flags[0], f1 = flags[1];
  for (int i = blockIdx.x * blockDim.x + threadIdx.x; i < T_DIM * B_DIM;
       i += gridDim.x * blockDim.x)
    rst8[i] = (unsigned char)read_reset(rst, f0, f1, i);
}

// Pack WiT (768x256 bf16, transposed Wi) and Wpk A-frags: frag(dt,ks) elem (l,j) =
// W[ks*32 + (l>>4)*8 + j][dt*16 + (l&15)]. dt 0-15: Whr, 16-31: Whz, 32-47: Whn.
__global__ void pack_weights(const float* __restrict__ Wi,
                             const float* __restrict__ Whr,
                             const float* __restrict__ Whz,
                             const float* __restrict__ Whn,
                             unsigned short* __restrict__ WiT,
                             unsigned short* __restrict__ Wpk) {
  int gid = blockIdx.x * 256 + threadIdx.x;
  const int NE = 768 * 256;
  if (gid < NE) {
    int n = gid >> 8, k = gid & 255;
    WiT[gid] = f2bf(Wi[k * 768 + n]);
  } else if (gid < 2 * NE) {
    int g = gid - NE;
    int j = g & 7, l = (g >> 3) & 63, ks = (g >> 9) & 7, nt = g >> 12;
    int k = ks * 32 + (l >> 4) * 8 + j;
    int col = nt * 16 + (l & 15);
    float w;
    if (col < 256)      w = Whr[k * 256 + col];
    else if (col < 512) w = Whz[k * 256 + col - 256];
    else                w = Whn[k * 256 + col - 512];
    Wpk[g] = f2bf(w);
  }
}

// xp[m][n] = x@Wi + bi, output bf16 in [T*B][768] layout. (unchanged)
__global__ __launch_bounds__(256) void gemm_xp(
    const float* __restrict__ x, const unsigned short* __restrict__ WiT,
    const float* __restrict__ bi, unsigned short* __restrict__ xp) {
  __shared__ __align__(16) unsigned short Al[128 * 64];
  __shared__ __align__(16) unsigned short Bl[128 * 64];
  const int tid = threadIdx.x;
  const int l = tid & 63, wid = tid >> 6;
  const int wm = wid >> 1, wn = wid & 1;
  const int n0 = blockIdx.x * 128;
  const long m0 = (long)blockIdx.y * 128;
  f32x4 acc[4][4] = {};
  for (int kb = 0; kb < 4; ++kb) {
    const int k0 = kb * 64;
    if (kb) __syncthreads();
#pragma unroll
    for (int i = 0; i < 8; ++i) {
      int fidx = i * 256 + tid;
      int row = fidx >> 4, kf = fidx & 15;
      float4 v = *(const float4*)&x[(m0 + row) * 256 + k0 + kf * 4];
      uint2 p;
      p.x = f2bf(v.x) | ((unsigned)f2bf(v.y) << 16);
      p.y = f2bf(v.z) | ((unsigned)f2bf(v.w) << 16);
      int byte = (row * 128 + kf * 8) ^ ((row & 7) << 4);
      *(uint2*)((char*)Al + byte) = p;
    }
#pragma unroll
    for (int i = 0; i < 4; ++i) {
      int cidx = i * 256 + tid;
      int row = cidx >> 3, kc = cidx & 7;
      short8 v = *(const short8*)&WiT[(n0 + row) * 256 + k0 + kc * 8];
      int byte = (row * 128 + kc * 16) ^ ((row & 7) << 4);
      *(short8*)((char*)Bl + byte) = v;
    }
    __syncthreads();
#pragma unroll
    for (int kk = 0; kk < 2; ++kk) {
      short8 af[4], bfv[4];
#pragma unroll
      for (int t = 0; t < 4; ++t) {
        int m = wm * 64 + t * 16 + (l & 15);
        af[t] = *(const short8*)((char*)Al + ((m * 128 + kk * 64 + (l >> 4) * 16) ^ ((m & 7) << 4)));
        int n = wn * 64 + t * 16 + (l & 15);
        bfv[t] = *(const short8*)((char*)Bl + ((n * 128 + kk * 64 + (l >> 4) * 16) ^ ((n & 7) << 4)));
      }
#pragma unroll
      for (int tm = 0; tm < 4; ++tm)
#pragma unroll
        for (int tn = 0; tn < 4; ++tn)
          acc[tm][tn] = __builtin_amdgcn_mfma_f32_16x16x32_bf16(af[tm], bfv[tn], acc[tm][tn], 0, 0, 0);
    }
  }
#pragma unroll
  for (int tn = 0; tn < 4; ++tn) {
    int n = n0 + wn * 64 + tn * 16 + (l & 15);
    float bv = bi[n];
#pragma unroll
    for (int tm = 0; tm < 4; ++tm) {
#pragma unroll
      for (int r = 0; r < 4; ++r) {
        long m = m0 + wm * 64 + tm * 16 + (l >> 4) * 4 + r;
        xp[m * 768 + n] = f2bf(acc[tm][tn][r] + bv);
      }
    }
  }
}

// Recurrent scan v3. 32 WGs x 8 batch rows x 512 threads (8 waves).
// Wave w owns d-cols [w*32, w*32+32) of all 3 gates: tiles r:{2w,2w+1},
// z:{16+2w,+1}, n:{32+2w,+1} — all 48 frags in VGPRs.
// acc[j] = mfma(Wfrag, hfrag): D col = batch (l&15; 0-7 valid), row = grp*4+r.
// After MFMA, DPP row_shr:8 moves odd-tile accs to lanes 8-15 so every lane
// gates 4 elements: (b_eff = p&7, d = w*32 + (p>>3)*16 + grp*4), p = l&15.
__global__ __launch_bounds__(512, 2) void rnn_scan(
    const unsigned short* __restrict__ xp, const unsigned char* __restrict__ rst8,
    const float* __restrict__ bhn, const unsigned short* __restrict__ Wpk,
    float* __restrict__ y, float* __restrict__ hws, int t0, int Tc) {
  __shared__ __align__(16) unsigned short hb16[2][16 * 256];  // 16 KB dbuf, XOR-swz
  const int tid = threadIdx.x;
  const int l = tid & 63, w = tid >> 6;
  const int p = l & 15, grp = l >> 4;
  const int b = p & 7, hi = p >> 3;
  const int B0 = blockIdx.x * 8;
  const int swf = (p & 7) << 4;      // swizzle for frag read (row = l&15)
  const int d0 = w * 32 + hi * 16 + grp * 4;  // this thread's 4 output d's

  // ---- all 48 weight frags into registers (192 VGPR) ----
  short8 wreg[48];
#pragma unroll
  for (int t = 0; t < 6; ++t) {
    int dt = (t >> 1) * 16 + w * 2 + (t & 1);  // t: 0,1=r 2,3=z 4,5=n (lo,hi)
#pragma unroll
    for (int kk = 0; kk < 8; ++kk)
      wreg[t * 8 + kk] = *(const short8*)&Wpk[((dt * 8 + kk) * 64 + l) * 8];
  }
  float4 bh = *(const float4*)&bhn[d0];

  // ---- init h (this thread's 4 elems) + hb16[0] ----
  float4 h = {0.f, 0.f, 0.f, 0.f};
  if (t0 > 0) {
    h = *(const float4*)&hws[(B0 + b) * 256 + d0];
    if (rst8[t0 * 256 + B0 + b]) h = {0.f, 0.f, 0.f, 0.f};
  }
  {
    uint2 hp;
    hp.x = f2bf(h.x) | ((unsigned)f2bf(h.y) << 16);
    hp.y = f2bf(h.z) | ((unsigned)f2bf(h.w) << 16);
    *(uint2*)((char*)&hb16[0][0] + ((b * 512 + d0 * 2) ^ (b << 4))) = hp;
  }
  __syncthreads();

  // ---- prefetch xp + reset for step 0 ----
  const unsigned short* xrow = xp + ((long)0 * 256 + B0 + b) * 768 + d0;
  uint2 xr_ = *(const uint2*)(xrow);
  uint2 xz_ = *(const uint2*)(xrow + 256);
  uint2 xn_ = *(const uint2*)(xrow + 512);
  int rstn = (t0 + 1 < T_DIM) ? (int)rst8[(t0 + 1) * 256 + B0 + b] : 0;

  for (int ts = 0; ts < Tc; ++ts) {
    const int cur = ts & 1, nxt = cur ^ 1;
    const char* hb = (const char*)&hb16[cur][0];
    // h frags: lane l reads h[batch=p][k = kk*32 + grp*8 + j], ring-3 prefetch
    short8 hfr[3];
#define LD_H(k) (*(const short8*)(hb + ((p * 512 + (k) * 64 + grp * 16) ^ swf)))
    hfr[0] = LD_H(0);
    hfr[1] = LD_H(1);
    f32x4 acc[6] = {};
#pragma unroll
    for (int kk = 0; kk < 8; ++kk) {
      if (kk + 2 < 8) hfr[(kk + 2) % 3] = LD_H(kk + 2);
      const int s = kk % 3;
      acc[0] = __builtin_amdgcn_mfma_f32_16x16x32_bf16(wreg[kk],      hfr[s], acc[0], 0, 0, 0);
      acc[1] = __builtin_amdgcn_mfma_f32_16x16x32_bf16(wreg[8 + kk],  hfr[s], acc[1], 0, 0, 0);
      acc[2] = __builtin_amdgcn_mfma_f32_16x16x32_bf16(wreg[16 + kk], hfr[s], acc[2], 0, 0, 0);
      acc[3] = __builtin_amdgcn_mfma_f32_16x16x32_bf16(wreg[24 + kk], hfr[s], acc[3], 0, 0, 0);
      acc[4] = __builtin_amdgcn_mfma_f32_16x16x32_bf16(wreg[32 + kk], hfr[s], acc[4], 0, 0, 0);
      acc[5] = __builtin_amdgcn_mfma_f32_16x16x32_bf16(wreg[40 + kk], hfr[s], acc[5], 0, 0, 0);
    }
#undef LD_H
    // ---- DPP: lanes p>=8 take odd-tile accs from lane p-8 ----
    float aR[4], aZ[4], aN[4];
#pragma unroll
    for (int r = 0; r < 4; ++r) {
      aR[r] = take_hi(acc[0][r], acc[1][r]);
      aZ[r] = take_hi(acc[2][r], acc[3][r]);
      aN[r] = take_hi(acc[4][r], acc[5][r]);
    }
    // ---- gates: 4 elements per thread, all in registers ----
    const int tg = t0 + ts;
    float4 o;
#pragma unroll
    for (int r = 0; r < 4; ++r) {
      float rg = sigm(bfx(xr_, r) + aR[r]);
      float zg = sigm(bfx(xz_, r) + aZ[r]);
      float ng = tanh_(bfx(xn_, r) + rg * (aN[r] + bh[r]));
      o[r] = (1.f - zg) * ng + zg * h[r];
    }
    *(float4*)&y[((long)tg * 256 + B0 + b) * 256 + d0] = o;
    // carry (mask with next step's reset), write hb16[nxt]
    const float m = rstn ? 0.f : 1.f;
    h.x = o.x * m; h.y = o.y * m; h.z = o.z * m; h.w = o.w * m;
    {
      uint2 hp;
      hp.x = f2bf(h.x) | ((unsigned)f2bf(h.y) << 16);
      hp.y = f2bf(h.z) | ((unsigned)f2bf(h.w) << 16);
      *(uint2*)((char*)&hb16[nxt][0] + ((b * 512 + d0 * 2) ^ (b << 4))) = hp;
    }
    // ---- prefetch next step (survives the raw barrier: vmcnt not drained) ----
    if (ts + 1 < Tc) {
      const unsigned short* xn_p = xp + ((long)(ts + 1) * 256 + B0 + b) * 768 + d0;
      xr_ = *(const uint2*)(xn_p);
      xz_ = *(const uint2*)(xn_p + 256);
      xn_ = *(const uint2*)(xn_p + 512);
      rstn = (tg + 2 < T_DIM) ? (int)rst8[(tg + 2) * 256 + B0 + b] : 0;
    }
    asm volatile("s_waitcnt lgkmcnt(0)" ::: "memory");
    __builtin_amdgcn_s_barrier();
  }
  *(float4*)&hws[(B0 + b) * 256 + d0] = h;
}

extern "C" void kernel_launch(void* const* d_in, const int* in_sizes, int n_in,
                              void* d_out, int out_size, void* d_ws, size_t ws_size,
                              hipStream_t stream) {
  const float* x    = (const float*)d_in[0];
  const void*  rst  = d_in[1];
  const float* Wi   = (const float*)d_in[2];
  const float* bi   = (const float*)d_in[3];
  const float* Whr  = (const float*)d_in[4];
  const float* Whz  = (const float*)d_in[5];
  const float* Whn  = (const float*)d_in[6];
  const float* bhn  = (const float*)d_in[7];
  float* y = (float*)d_out;

  char* ws = (char*)d_ws;
  unsigned short* Wpk = (unsigned short*)(ws);              // 393216 B
  unsigned short* WiT = (unsigned short*)(ws + 393216);     // 393216 B
  float* hws          = (float*)(ws + 786432);              // 262144 B
  int* flags          = (int*)(ws + 1048576);               // 256 B slot
  unsigned char* rst8 = (unsigned char*)(ws + 1048832);     // 262144 B
  unsigned short* xpb = (unsigned short*)(ws + 1310976);

  const size_t fixed = 1310976;
  int Tc = T_DIM;
  while (Tc > 1 && fixed + (size_t)Tc * B_DIM * 768 * 2 > ws_size) Tc >>= 1;

  hipMemsetAsync(flags, 0, 8, stream);
  detect_resets<<<64, 256, 0, stream>>>((const int*)rst, T_DIM * B_DIM / 4, flags);
  convert_resets<<<256, 256, 0, stream>>>(rst, flags, rst8);
  pack_weights<<<1536, 256, 0, stream>>>(Wi, Whr, Whz, Whn, WiT, Wpk);
  for (int t0 = 0; t0 < T_DIM; t0 += Tc) {
    gemm_xp<<<dim3(6, Tc * 2), 256, 0, stream>>>(x + (long)t0 * B_DIM * D_DIM, WiT, bi, xpb);
    rnn_scan<<<32, 512, 0, stream>>>(xpb, rst8, bhn, Wpk, y, hws, t0, Tc);
  }
}

// Round 4
// 1892.798 us; speedup vs baseline: 3.5144x; 1.5459x over previous
//
#include <hip/hip_runtime.h>

// GRU scan: T=1024, B=256, D=256.
// v4: v3 structure + trans-pipe reduction: weights/xp pre-scaled by -log2e (r,z)
// and +2log2e (n) so gates are exp2-direct; ONE v_rcp for all 8 sigmoid denoms
// + ONE for 4 tanh denoms (prefix/suffix inverse trick); cvt_pk_bf16 asm pack;
// setprio(1) around MFMA cluster. Trans ops/thread: 24 -> 14.

typedef __attribute__((ext_vector_type(8))) short short8;
typedef __attribute__((ext_vector_type(4))) float f32x4;

#define T_DIM 1024
#define B_DIM 256
#define D_DIM 256
#define SCL_RZ (-1.44269504f)   // -log2(e): sigm(x) = 1/(1+exp2(x*SCL_RZ))
#define SCL_N  (2.88539008f)    // 2*log2(e): tanh(v) = 1-2/(1+exp2(v*SCL_N))

__device__ __forceinline__ unsigned short f2bf(float f) {
  union { float f; unsigned u; } c; c.f = f;
  unsigned r = c.u + 0x7FFFu + ((c.u >> 16) & 1u);  // RNE
  return (unsigned short)(r >> 16);
}
__device__ __forceinline__ float u2f(unsigned u) {
  union { unsigned u; float f; } c; c.u = u;
  return c.f;
}
// lanes p>=8 (p = lane&15) take `other` from lane p-8; lanes p<8 keep `own`.
__device__ __forceinline__ float take_hi(float own, float other) {
  union { float f; int i; } o, s, r;
  o.f = own; s.f = other;
  r.i = __builtin_amdgcn_update_dpp(o.i, s.i, 0x118, 0xF, 0xC, false);
  return r.f;
}

// resets dtype ambiguous (reference dtype bool). flags[0]=float32, flags[1]=bytes.
__global__ void detect_resets(const int* __restrict__ r, int n, int* __restrict__ flags) {
  int isf = 0, oth = 0;
  for (int i = blockIdx.x * blockDim.x + threadIdx.x; i < n; i += gridDim.x * blockDim.x) {
    int v = r[i];
    if (v == 0x3F800000) isf = 1;
    else if (v != 0 && v != 1) oth = 1;
  }
  if (isf) atomicOr(&flags[0], 1);
  if (oth) atomicOr(&flags[1], 1);
}

__device__ __forceinline__ int read_reset(const void* r, int f0, int f1, int idx) {
  if (f0) return ((const float*)r)[idx] != 0.0f;
  if (f1) return ((const unsigned char*)r)[idx] != 0;
  return ((const int*)r)[idx] != 0;
}

__global__ void convert_resets(const void* __restrict__ rst, const int* __restrict__ flags,
                               unsigned char* __restrict__ rst8) {
  int f0 = flags[0], f1 = flags[1];
  for (int i = blockIdx.x * blockDim.x + threadIdx.x; i < T_DIM * B_DIM;
       i += gridDim.x * blockDim.x)
    rst8[i] = (unsigned char)read_reset(rst, f0, f1, i);
}

// Pack WiT (768x256 bf16, transposed Wi, PRE-SCALED per output col) and Wpk A-frags
// (PRE-SCALED): frag(dt,ks) elem (l,j) = scl(dt)*W[ks*32+(l>>4)*8+j][dt*16+(l&15)].
__global__ void pack_weights(const float* __restrict__ Wi,
                             const float* __restrict__ Whr,
                             const float* __restrict__ Whz,
                             const float* __restrict__ Whn,
                             unsigned short* __restrict__ WiT,
                             unsigned short* __restrict__ Wpk) {
  int gid = blockIdx.x * 256 + threadIdx.x;
  const int NE = 768 * 256;
  if (gid < NE) {
    int n = gid >> 8, k = gid & 255;
    float scl = (n < 512) ? SCL_RZ : SCL_N;
    WiT[gid] = f2bf(Wi[k * 768 + n] * scl);
  } else if (gid < 2 * NE) {
    int g = gid - NE;
    int j = g & 7, l = (g >> 3) & 63, ks = (g >> 9) & 7, nt = g >> 12;
    int k = ks * 32 + (l >> 4) * 8 + j;
    int col = nt * 16 + (l & 15);
    float w;
    if (col < 256)      w = Whr[k * 256 + col] * SCL_RZ;
    else if (col < 512) w = Whz[k * 256 + col - 256] * SCL_RZ;
    else                w = Whn[k * 256 + col - 512] * SCL_N;
    Wpk[g] = f2bf(w);
  }
}

// xp[m][n] = (x@Wi_scaled) + bi[n]*scl(n), output bf16 [T*B][768].
__global__ __launch_bounds__(256) void gemm_xp(
    const float* __restrict__ x, const unsigned short* __restrict__ WiT,
    const float* __restrict__ bi, unsigned short* __restrict__ xp) {
  __shared__ __align__(16) unsigned short Al[128 * 64];
  __shared__ __align__(16) unsigned short Bl[128 * 64];
  const int tid = threadIdx.x;
  const int l = tid & 63, wid = tid >> 6;
  const int wm = wid >> 1, wn = wid & 1;
  const int n0 = blockIdx.x * 128;
  const long m0 = (long)blockIdx.y * 128;
  f32x4 acc[4][4] = {};
  for (int kb = 0; kb < 4; ++kb) {
    const int k0 = kb * 64;
    if (kb) __syncthreads();
#pragma unroll
    for (int i = 0; i < 8; ++i) {
      int fidx = i * 256 + tid;
      int row = fidx >> 4, kf = fidx & 15;
      float4 v = *(const float4*)&x[(m0 + row) * 256 + k0 + kf * 4];
      uint2 p;
      p.x = f2bf(v.x) | ((unsigned)f2bf(v.y) << 16);
      p.y = f2bf(v.z) | ((unsigned)f2bf(v.w) << 16);
      int byte = (row * 128 + kf * 8) ^ ((row & 7) << 4);
      *(uint2*)((char*)Al + byte) = p;
    }
#pragma unroll
    for (int i = 0; i < 4; ++i) {
      int cidx = i * 256 + tid;
      int row = cidx >> 3, kc = cidx & 7;
      short8 v = *(const short8*)&WiT[(n0 + row) * 256 + k0 + kc * 8];
      int byte = (row * 128 + kc * 16) ^ ((row & 7) << 4);
      *(short8*)((char*)Bl + byte) = v;
    }
    __syncthreads();
#pragma unroll
    for (int kk = 0; kk < 2; ++kk) {
      short8 af[4], bfv[4];
#pragma unroll
      for (int t = 0; t < 4; ++t) {
        int m = wm * 64 + t * 16 + (l & 15);
        af[t] = *(const short8*)((char*)Al + ((m * 128 + kk * 64 + (l >> 4) * 16) ^ ((m & 7) << 4)));
        int n = wn * 64 + t * 16 + (l & 15);
        bfv[t] = *(const short8*)((char*)Bl + ((n * 128 + kk * 64 + (l >> 4) * 16) ^ ((n & 7) << 4)));
      }
#pragma unroll
      for (int tm = 0; tm < 4; ++tm)
#pragma unroll
        for (int tn = 0; tn < 4; ++tn)
          acc[tm][tn] = __builtin_amdgcn_mfma_f32_16x16x32_bf16(af[tm], bfv[tn], acc[tm][tn], 0, 0, 0);
    }
  }
#pragma unroll
  for (int tn = 0; tn < 4; ++tn) {
    int n = n0 + wn * 64 + tn * 16 + (l & 15);
    float bscl = bi[n] * ((n < 512) ? SCL_RZ : SCL_N);
#pragma unroll
    for (int tm = 0; tm < 4; ++tm) {
#pragma unroll
      for (int r = 0; r < 4; ++r) {
        long m = m0 + wm * 64 + tm * 16 + (l >> 4) * 4 + r;
        xp[m * 768 + n] = f2bf(acc[tm][tn][r] + bscl);
      }
    }
  }
}

// Recurrent scan v4. 32 WGs x 8 batch rows x 512 threads. Same layout as v3;
// gate math rewritten: exp2-direct (pre-scaled inputs), batched reciprocals.
__global__ __launch_bounds__(512, 2) void rnn_scan(
    const unsigned short* __restrict__ xp, const unsigned char* __restrict__ rst8,
    const float* __restrict__ bhn, const unsigned short* __restrict__ Wpk,
    float* __restrict__ y, float* __restrict__ hws, int t0, int Tc) {
  __shared__ __align__(16) unsigned short hb16[2][16 * 256];  // 16 KB dbuf, XOR-swz
  const int tid = threadIdx.x;
  const int l = tid & 63, w = tid >> 6;
  const int p = l & 15, grp = l >> 4;
  const int b = p & 7, hi = p >> 3;
  const int B0 = blockIdx.x * 8;
  const int swf = (p & 7) << 4;
  const int d0 = w * 32 + hi * 16 + grp * 4;

  // ---- all 48 weight frags into registers ----
  short8 wreg[48];
#pragma unroll
  for (int t = 0; t < 6; ++t) {
    int dt = (t >> 1) * 16 + w * 2 + (t & 1);
#pragma unroll
    for (int kk = 0; kk < 8; ++kk)
      wreg[t * 8 + kk] = *(const short8*)&Wpk[((dt * 8 + kk) * 64 + l) * 8];
  }
  float bh_[4];
  {
    float4 bv = *(const float4*)&bhn[d0];
    bh_[0] = bv.x * SCL_N; bh_[1] = bv.y * SCL_N;
    bh_[2] = bv.z * SCL_N; bh_[3] = bv.w * SCL_N;
  }

  // ---- init h + hb16[0] ----
  float h_[4] = {0.f, 0.f, 0.f, 0.f};
  if (t0 > 0) {
    float4 hv = *(const float4*)&hws[(B0 + b) * 256 + d0];
    if (!rst8[t0 * 256 + B0 + b]) { h_[0]=hv.x; h_[1]=hv.y; h_[2]=hv.z; h_[3]=hv.w; }
  }
  {
    unsigned hp0, hp1;
    asm("v_cvt_pk_bf16_f32 %0, %1, %2" : "=v"(hp0) : "v"(h_[0]), "v"(h_[1]));
    asm("v_cvt_pk_bf16_f32 %0, %1, %2" : "=v"(hp1) : "v"(h_[2]), "v"(h_[3]));
    uint2 hp; hp.x = hp0; hp.y = hp1;
    *(uint2*)((char*)&hb16[0][0] + ((b * 512 + d0 * 2) ^ (b << 4))) = hp;
  }
  __syncthreads();

  // ---- prefetch xp + reset for step 0 ----
  const unsigned short* xpp = xp + ((long)(B0 + b)) * 768 + d0;
  float* yp = y + ((long)t0 * 256 + B0 + b) * 256 + d0;
  uint2 xr_ = *(const uint2*)(xpp);
  uint2 xz_ = *(const uint2*)(xpp + 256);
  uint2 xn_ = *(const uint2*)(xpp + 512);
  int rstn = (t0 + 1 < T_DIM) ? (int)rst8[(t0 + 1) * 256 + B0 + b] : 0;

  for (int ts = 0; ts < Tc; ++ts) {
    const int cur = ts & 1, nxt = cur ^ 1;
    const char* hb = (const char*)&hb16[cur][0];
    short8 hfr[3];
#define LD_H(k) (*(const short8*)(hb + ((p * 512 + (k) * 64 + grp * 16) ^ swf)))
    hfr[0] = LD_H(0);
    hfr[1] = LD_H(1);
    f32x4 acc[6] = {};
    __builtin_amdgcn_s_setprio(1);
#pragma unroll
    for (int kk = 0; kk < 8; ++kk) {
      if (kk + 2 < 8) hfr[(kk + 2) % 3] = LD_H(kk + 2);
      const int s = kk % 3;
      acc[0] = __builtin_amdgcn_mfma_f32_16x16x32_bf16(wreg[kk],      hfr[s], acc[0], 0, 0, 0);
      acc[1] = __builtin_amdgcn_mfma_f32_16x16x32_bf16(wreg[8 + kk],  hfr[s], acc[1], 0, 0, 0);
      acc[2] = __builtin_amdgcn_mfma_f32_16x16x32_bf16(wreg[16 + kk], hfr[s], acc[2], 0, 0, 0);
      acc[3] = __builtin_amdgcn_mfma_f32_16x16x32_bf16(wreg[24 + kk], hfr[s], acc[3], 0, 0, 0);
      acc[4] = __builtin_amdgcn_mfma_f32_16x16x32_bf16(wreg[32 + kk], hfr[s], acc[4], 0, 0, 0);
      acc[5] = __builtin_amdgcn_mfma_f32_16x16x32_bf16(wreg[40 + kk], hfr[s], acc[5], 0, 0, 0);
    }
    __builtin_amdgcn_s_setprio(0);
#undef LD_H
    // ---- DPP redistribution ----
    float aR[4], aZ[4], aN[4];
#pragma unroll
    for (int r = 0; r < 4; ++r) {
      aR[r] = take_hi(acc[0][r], acc[1][r]);
      aZ[r] = take_hi(acc[2][r], acc[3][r]);
      aN[r] = take_hi(acc[4][r], acc[5][r]);
    }
    // ---- gates: pre-scaled exp2 form, batched reciprocals ----
    float xrf[4] = {u2f(xr_.x << 16), u2f(xr_.x & 0xffff0000u),
                    u2f(xr_.y << 16), u2f(xr_.y & 0xffff0000u)};
    float xzf[4] = {u2f(xz_.x << 16), u2f(xz_.x & 0xffff0000u),
                    u2f(xz_.y << 16), u2f(xz_.y & 0xffff0000u)};
    float xnf[4] = {u2f(xn_.x << 16), u2f(xn_.x & 0xffff0000u),
                    u2f(xn_.y << 16), u2f(xn_.y & 0xffff0000u)};
    float den[8];
#pragma unroll
    for (int r = 0; r < 4; ++r) {
      den[r]     = 1.0f + exp2f(fminf(xrf[r] + aR[r], 14.f));  // sigm_r denom
      den[4 + r] = 1.0f + exp2f(fminf(xzf[r] + aZ[r], 14.f));  // sigm_z denom
    }
    // inv8: one rcp for all 8 denominators
    float inv[8];
    {
      float p0 = den[0], p1 = p0 * den[1], p2 = p1 * den[2], p3 = p2 * den[3];
      float p4 = p3 * den[4], p5 = p4 * den[5], p6 = p5 * den[6];
      float s = __builtin_amdgcn_rcpf(p6 * den[7]);
      inv[7] = p6 * s; s *= den[7];
      inv[6] = p5 * s; s *= den[6];
      inv[5] = p4 * s; s *= den[5];
      inv[4] = p3 * s; s *= den[4];
      inv[3] = p2 * s; s *= den[3];
      inv[2] = p1 * s; s *= den[2];
      inv[1] = p0 * s; s *= den[1];
      inv[0] = s;
    }
    float cden[4];
#pragma unroll
    for (int r = 0; r < 4; ++r) {
      float t = aN[r] + bh_[r];
      float v = fmaf(inv[r], t, xnf[r]);   // r-gate = inv[r]; v pre-scaled by 2log2e
      cden[r] = 1.0f + exp2f(fminf(v, 14.f));
    }
    float ic[4];
    {
      float p0 = cden[0], p1 = p0 * cden[1], p2 = p1 * cden[2];
      float s = __builtin_amdgcn_rcpf(p2 * cden[3]);
      ic[3] = p2 * s; s *= cden[3];
      ic[2] = p1 * s; s *= cden[2];
      ic[1] = p0 * s; s *= cden[1];
      ic[0] = s;
    }
    float o_[4];
#pragma unroll
    for (int r = 0; r < 4; ++r) {
      float ng = fmaf(-2.0f, ic[r], 1.0f);          // tanh
      o_[r] = fmaf(inv[4 + r], h_[r] - ng, ng);     // o = n + z*(h-n)
    }
    float4 o4 = {o_[0], o_[1], o_[2], o_[3]};
    *(float4*)yp = o4;
    yp += 256 * 256;
    // carry (mask with next step's reset) + pack
    const float m = rstn ? 0.f : 1.f;
#pragma unroll
    for (int r = 0; r < 4; ++r) h_[r] = o_[r] * m;
    {
      unsigned hp0, hp1;
      asm("v_cvt_pk_bf16_f32 %0, %1, %2" : "=v"(hp0) : "v"(h_[0]), "v"(h_[1]));
      asm("v_cvt_pk_bf16_f32 %0, %1, %2" : "=v"(hp1) : "v"(h_[2]), "v"(h_[3]));
      uint2 hp; hp.x = hp0; hp.y = hp1;
      *(uint2*)((char*)&hb16[nxt][0] + ((b * 512 + d0 * 2) ^ (b << 4))) = hp;
    }
    // ---- prefetch next step (vmcnt NOT drained at barrier) ----
    if (ts + 1 < Tc) {
      const unsigned short* xn_p = xpp + (long)(ts + 1) * (256 * 768);
      xr_ = *(const uint2*)(xn_p);
      xz_ = *(const uint2*)(xn_p + 256);
      xn_ = *(const uint2*)(xn_p + 512);
      int tg = t0 + ts;
      rstn = (tg + 2 < T_DIM) ? (int)rst8[(tg + 2) * 256 + B0 + b] : 0;
    }
    asm volatile("s_waitcnt lgkmcnt(0)" ::: "memory");
    __builtin_amdgcn_s_barrier();
  }
  float4 hv = {h_[0], h_[1], h_[2], h_[3]};
  *(float4*)&hws[(B0 + b) * 256 + d0] = hv;
}

extern "C" void kernel_launch(void* const* d_in, const int* in_sizes, int n_in,
                              void* d_out, int out_size, void* d_ws, size_t ws_size,
                              hipStream_t stream) {
  const float* x    = (const float*)d_in[0];
  const void*  rst  = d_in[1];
  const float* Wi   = (const float*)d_in[2];
  const float* bi   = (const float*)d_in[3];
  const float* Whr  = (const float*)d_in[4];
  const float* Whz  = (const float*)d_in[5];
  const float* Whn  = (const float*)d_in[6];
  const float* bhn  = (const float*)d_in[7];
  float* y = (float*)d_out;

  char* ws = (char*)d_ws;
  unsigned short* Wpk = (unsigned short*)(ws);              // 393216 B
  unsigned short* WiT = (unsigned short*)(ws + 393216);     // 393216 B
  float* hws          = (float*)(ws + 786432);              // 262144 B
  int* flags          = (int*)(ws + 1048576);               // 256 B slot
  unsigned char* rst8 = (unsigned char*)(ws + 1048832);     // 262144 B
  unsigned short* xpb = (unsigned short*)(ws + 1310976);

  const size_t fixed = 1310976;
  int Tc = T_DIM;
  while (Tc > 1 && fixed + (size_t)Tc * B_DIM * 768 * 2 > ws_size) Tc >>= 1;

  hipMemsetAsync(flags, 0, 8, stream);
  detect_resets<<<64, 256, 0, stream>>>((const int*)rst, T_DIM * B_DIM / 4, flags);
  convert_resets<<<256, 256, 0, stream>>>(rst, flags, rst8);
  pack_weights<<<1536, 256, 0, stream>>>(Wi, Whr, Whz, Whn, WiT, Wpk);
  for (int t0 = 0; t0 < T_DIM; t0 += Tc) {
    gemm_xp<<<dim3(6, Tc * 2), 256, 0, stream>>>(x + (long)t0 * B_DIM * D_DIM, WiT, bi, xpb);
    rnn_scan<<<32, 512, 0, stream>>>(xpb, rst8, bhn, Wpk, y, hws, t0, Tc);
  }
}

// Round 5
// 1581.149 us; speedup vs baseline: 4.2071x; 1.1971x over previous
//
#include <hip/hip_runtime.h>

// GRU scan: T=1024, B=256, D=256.
// v5: 64 WGs x 4 batch rows. MFMA floor per SIMD is fixed (96 MFMA x ~19.4cyc);
// halving rows/WG halves gate VALU/trans per thread (2 elems, 8 trans ops) so
// VALU hides under the MFMA floor. Two-stage DPP fold (shr:4 then shr:8) keeps
// all 64 lanes busy in the gate phase. gemm_xp gets a bijective XCD-affine
// remap so the 6 N-blocks of an M-block share one XCD's L2 (x read ~once).

typedef __attribute__((ext_vector_type(8))) short short8;
typedef __attribute__((ext_vector_type(4))) float f32x4;

#define T_DIM 1024
#define B_DIM 256
#define D_DIM 256
#define SCL_RZ (-1.44269504f)   // -log2(e): sigm(x) = 1/(1+exp2(x*SCL_RZ))
#define SCL_N  (2.88539008f)    // 2*log2(e): tanh(v) = 1-2/(1+exp2(v*SCL_N))

__device__ __forceinline__ unsigned short f2bf(float f) {
  union { float f; unsigned u; } c; c.f = f;
  unsigned r = c.u + 0x7FFFu + ((c.u >> 16) & 1u);  // RNE
  return (unsigned short)(r >> 16);
}
__device__ __forceinline__ float u2f(unsigned u) {
  union { unsigned u; float f; } c; c.u = u;
  return c.f;
}
// lanes q>=4 in each 8 (banks 1,3) take src from lane q-4 (tile-odd fold)
__device__ __forceinline__ float dpp_shr4(float own, float src) {
  union { float f; int i; } o, s, r;
  o.f = own; s.f = src;
  r.i = __builtin_amdgcn_update_dpp(o.i, s.i, 0x114, 0xF, 0xA, false);
  return r.f;
}
// lanes q>=8 (banks 2,3) take src from lane q-8 (reg-pair fold)
__device__ __forceinline__ float dpp_shr8(float own, float src) {
  union { float f; int i; } o, s, r;
  o.f = own; s.f = src;
  r.i = __builtin_amdgcn_update_dpp(o.i, s.i, 0x118, 0xF, 0xC, false);
  return r.f;
}

// resets dtype ambiguous (reference dtype bool). flags[0]=float32, flags[1]=bytes.
__global__ void detect_resets(const int* __restrict__ r, int n, int* __restrict__ flags) {
  int isf = 0, oth = 0;
  for (int i = blockIdx.x * blockDim.x + threadIdx.x; i < n; i += gridDim.x * blockDim.x) {
    int v = r[i];
    if (v == 0x3F800000) isf = 1;
    else if (v != 0 && v != 1) oth = 1;
  }
  if (isf) atomicOr(&flags[0], 1);
  if (oth) atomicOr(&flags[1], 1);
}

__device__ __forceinline__ int read_reset(const void* r, int f0, int f1, int idx) {
  if (f0) return ((const float*)r)[idx] != 0.0f;
  if (f1) return ((const unsigned char*)r)[idx] != 0;
  return ((const int*)r)[idx] != 0;
}

__global__ void convert_resets(const void* __restrict__ rst, const int* __restrict__ flags,
                               unsigned char* __restrict__ rst8) {
  int f0 = flags[0], f1 = flags[1];
  for (int i = blockIdx.x * blockDim.x + threadIdx.x; i < T_DIM * B_DIM;
       i += gridDim.x * blockDim.x)
    rst8[i] = (unsigned char)read_reset(rst, f0, f1, i);
}

// Pack WiT (768x256 bf16, transposed Wi, PRE-SCALED per output col) and Wpk A-frags
// (PRE-SCALED): frag(dt,ks) elem (l,j) = scl(dt)*W[ks*32+(l>>4)*8+j][dt*16+(l&15)].
__global__ void pack_weights(const float* __restrict__ Wi,
                             const float* __restrict__ Whr,
                             const float* __restrict__ Whz,
                             const float* __restrict__ Whn,
                             unsigned short* __restrict__ WiT,
                             unsigned short* __restrict__ Wpk) {
  int gid = blockIdx.x * 256 + threadIdx.x;
  const int NE = 768 * 256;
  if (gid < NE) {
    int n = gid >> 8, k = gid & 255;
    float scl = (n < 512) ? SCL_RZ : SCL_N;
    WiT[gid] = f2bf(Wi[k * 768 + n] * scl);
  } else if (gid < 2 * NE) {
    int g = gid - NE;
    int j = g & 7, l = (g >> 3) & 63, ks = (g >> 9) & 7, nt = g >> 12;
    int k = ks * 32 + (l >> 4) * 8 + j;
    int col = nt * 16 + (l & 15);
    float w;
    if (col < 256)      w = Whr[k * 256 + col] * SCL_RZ;
    else if (col < 512) w = Whz[k * 256 + col - 256] * SCL_RZ;
    else                w = Whn[k * 256 + col - 512] * SCL_N;
    Wpk[g] = f2bf(w);
  }
}

// xp[m][n] = (x@Wi_scaled) + bi[n]*scl(n), output bf16 [T*B][768].
// 1D grid, XCD-affine remap: XCD c (= L%8) gets a contiguous chunk of (m,n)
// tiles ordered n-fastest -> the 6 N-blocks of an M-block hit the same L2.
__global__ __launch_bounds__(256) void gemm_xp(
    const float* __restrict__ x, const unsigned short* __restrict__ WiT,
    const float* __restrict__ bi, unsigned short* __restrict__ xp) {
  __shared__ __align__(16) unsigned short Al[128 * 64];
  __shared__ __align__(16) unsigned short Bl[128 * 64];
  const int tid = threadIdx.x;
  const int l = tid & 63, wid = tid >> 6;
  const int wm = wid >> 1, wn = wid & 1;
  // bijective XCD remap (m204 form)
  const int L = blockIdx.x, nwg = gridDim.x;
  const int q = nwg >> 3, r8 = nwg & 7;
  const int c = L & 7, o = L >> 3;
  const int g = c * q + ((c < r8) ? c : r8) + o;
  const int n0 = (g % 6) * 128;
  const long m0 = (long)(g / 6) * 128;
  f32x4 acc[4][4] = {};
  for (int kb = 0; kb < 4; ++kb) {
    const int k0 = kb * 64;
    if (kb) __syncthreads();
#pragma unroll
    for (int i = 0; i < 8; ++i) {
      int fidx = i * 256 + tid;
      int row = fidx >> 4, kf = fidx & 15;
      float4 v = *(const float4*)&x[(m0 + row) * 256 + k0 + kf * 4];
      uint2 p;
      p.x = f2bf(v.x) | ((unsigned)f2bf(v.y) << 16);
      p.y = f2bf(v.z) | ((unsigned)f2bf(v.w) << 16);
      int byte = (row * 128 + kf * 8) ^ ((row & 7) << 4);
      *(uint2*)((char*)Al + byte) = p;
    }
#pragma unroll
    for (int i = 0; i < 4; ++i) {
      int cidx = i * 256 + tid;
      int row = cidx >> 3, kc = cidx & 7;
      short8 v = *(const short8*)&WiT[(n0 + row) * 256 + k0 + kc * 8];
      int byte = (row * 128 + kc * 16) ^ ((row & 7) << 4);
      *(short8*)((char*)Bl + byte) = v;
    }
    __syncthreads();
#pragma unroll
    for (int kk = 0; kk < 2; ++kk) {
      short8 af[4], bfv[4];
#pragma unroll
      for (int t = 0; t < 4; ++t) {
        int m = wm * 64 + t * 16 + (l & 15);
        af[t] = *(const short8*)((char*)Al + ((m * 128 + kk * 64 + (l >> 4) * 16) ^ ((m & 7) << 4)));
        int n = wn * 64 + t * 16 + (l & 15);
        bfv[t] = *(const short8*)((char*)Bl + ((n * 128 + kk * 64 + (l >> 4) * 16) ^ ((n & 7) << 4)));
      }
#pragma unroll
      for (int tm = 0; tm < 4; ++tm)
#pragma unroll
        for (int tn = 0; tn < 4; ++tn)
          acc[tm][tn] = __builtin_amdgcn_mfma_f32_16x16x32_bf16(af[tm], bfv[tn], acc[tm][tn], 0, 0, 0);
    }
  }
#pragma unroll
  for (int tn = 0; tn < 4; ++tn) {
    int n = n0 + wn * 64 + tn * 16 + (l & 15);
    float bscl = bi[n] * ((n < 512) ? SCL_RZ : SCL_N);
#pragma unroll
    for (int tm = 0; tm < 4; ++tm) {
#pragma unroll
      for (int r = 0; r < 4; ++r) {
        long m = m0 + wm * 64 + tm * 16 + (l >> 4) * 4 + r;
        xp[m * 768 + n] = f2bf(acc[tm][tn][r] + bscl);
      }
    }
  }
}

// Recurrent scan v5. 64 WGs x 4 batch rows x 512 threads (8 waves).
// Wave w owns d-cols [w*32, w*32+32) of all 3 gates (6 tiles, 48 frags in regs).
// acc[j] = mfma(Wfrag, hfrag): D col = batch (l&15; 0-3 valid), row = grp*4+r.
// Fold: shr:4 puts tile-odd cols into lanes 4-7; shr:8 moves regs 2-3 to lanes
// 8-15. Lane (grp,p): b = p&3, d = w*32 + ((p>>2)&1)*16 + grp*4 + (p>>3)*2, 2 elems.
__global__ __launch_bounds__(512, 2) void rnn_scan(
    const unsigned short* __restrict__ xp, const unsigned char* __restrict__ rst8,
    const float* __restrict__ bhn, const unsigned short* __restrict__ Wpk,
    float* __restrict__ y, float* __restrict__ hws, int t0, int Tc) {
  __shared__ __align__(16) unsigned short hb16[2][4 * 256];  // 4 KB dbuf, XOR-swz
  const int tid = threadIdx.x;
  const int l = tid & 63, w = tid >> 6;
  const int p = l & 15, grp = l >> 4;
  const int b = p & 3;
  const int B0 = blockIdx.x * 4;
  const int swb = (b << 4) | (b << 6);       // swizzle (bits 4-7, row-constant)
  const int d0 = w * 32 + ((p >> 2) & 1) * 16 + grp * 4 + (p >> 3) * 2;

  // ---- all 48 weight frags into registers ----
  short8 wreg[48];
#pragma unroll
  for (int t = 0; t < 6; ++t) {
    int dt = (t >> 1) * 16 + w * 2 + (t & 1);
#pragma unroll
    for (int kk = 0; kk < 8; ++kk)
      wreg[t * 8 + kk] = *(const short8*)&Wpk[((dt * 8 + kk) * 64 + l) * 8];
  }
  float bh_[2];
  {
    float2 bv = *(const float2*)&bhn[d0];
    bh_[0] = bv.x * SCL_N; bh_[1] = bv.y * SCL_N;
  }

  // ---- init h (2 elems) + hb16[0] ----
  float h_[2] = {0.f, 0.f};
  if (t0 > 0) {
    float2 hv = *(const float2*)&hws[(B0 + b) * 256 + d0];
    if (!rst8[t0 * 256 + B0 + b]) { h_[0] = hv.x; h_[1] = hv.y; }
  }
  {
    unsigned hp;
    asm("v_cvt_pk_bf16_f32 %0, %1, %2" : "=v"(hp) : "v"(h_[0]), "v"(h_[1]));
    *(unsigned*)((char*)&hb16[0][0] + ((b * 512 + d0 * 2) ^ swb)) = hp;
  }
  __syncthreads();

  // ---- prefetch xp + reset for step 0 ----
  const unsigned short* xpp = xp + ((long)(B0 + b)) * 768 + d0;
  float* yp = y + ((long)t0 * 256 + B0 + b) * 256 + d0;
  unsigned xr_ = *(const unsigned*)(xpp);
  unsigned xz_ = *(const unsigned*)(xpp + 256);
  unsigned xn_ = *(const unsigned*)(xpp + 512);
  int rstn = (t0 + 1 < T_DIM) ? (int)rst8[(t0 + 1) * 256 + B0 + b] : 0;

  for (int ts = 0; ts < Tc; ++ts) {
    const int cur = ts & 1, nxt = cur ^ 1;
    const char* hb = (const char*)&hb16[cur][0];
    short8 hfr[3];
#define LD_H(k) (*(const short8*)(hb + (((p & 3) * 512 + (k) * 64 + grp * 16) ^ swb)))
    hfr[0] = LD_H(0);
    hfr[1] = LD_H(1);
    f32x4 acc[6] = {};
    __builtin_amdgcn_s_setprio(1);
#pragma unroll
    for (int kk = 0; kk < 8; ++kk) {
      if (kk + 2 < 8) hfr[(kk + 2) % 3] = LD_H(kk + 2);
      const int s = kk % 3;
      acc[0] = __builtin_amdgcn_mfma_f32_16x16x32_bf16(wreg[kk],      hfr[s], acc[0], 0, 0, 0);
      acc[1] = __builtin_amdgcn_mfma_f32_16x16x32_bf16(wreg[8 + kk],  hfr[s], acc[1], 0, 0, 0);
      acc[2] = __builtin_amdgcn_mfma_f32_16x16x32_bf16(wreg[16 + kk], hfr[s], acc[2], 0, 0, 0);
      acc[3] = __builtin_amdgcn_mfma_f32_16x16x32_bf16(wreg[24 + kk], hfr[s], acc[3], 0, 0, 0);
      acc[4] = __builtin_amdgcn_mfma_f32_16x16x32_bf16(wreg[32 + kk], hfr[s], acc[4], 0, 0, 0);
      acc[5] = __builtin_amdgcn_mfma_f32_16x16x32_bf16(wreg[40 + kk], hfr[s], acc[5], 0, 0, 0);
    }
    __builtin_amdgcn_s_setprio(0);
#undef LD_H
    // ---- two-stage DPP fold: 6 tiles -> 2 elems/lane per gate ----
    float aR[2], aZ[2], aN[2];
    {
      float f0, f1, f2, f3;
      f0 = dpp_shr4(acc[0][0], acc[1][0]); f1 = dpp_shr4(acc[0][1], acc[1][1]);
      f2 = dpp_shr4(acc[0][2], acc[1][2]); f3 = dpp_shr4(acc[0][3], acc[1][3]);
      aR[0] = dpp_shr8(f0, f2); aR[1] = dpp_shr8(f1, f3);
      f0 = dpp_shr4(acc[2][0], acc[3][0]); f1 = dpp_shr4(acc[2][1], acc[3][1]);
      f2 = dpp_shr4(acc[2][2], acc[3][2]); f3 = dpp_shr4(acc[2][3], acc[3][3]);
      aZ[0] = dpp_shr8(f0, f2); aZ[1] = dpp_shr8(f1, f3);
      f0 = dpp_shr4(acc[4][0], acc[5][0]); f1 = dpp_shr4(acc[4][1], acc[5][1]);
      f2 = dpp_shr4(acc[4][2], acc[5][2]); f3 = dpp_shr4(acc[4][3], acc[5][3]);
      aN[0] = dpp_shr8(f0, f2); aN[1] = dpp_shr8(f1, f3);
    }
    // ---- gates: 2 elems, exp2-direct, batched reciprocals (6 exp2 + 2 rcp) ----
    float xrf[2] = {u2f(xr_ << 16), u2f(xr_ & 0xffff0000u)};
    float xzf[2] = {u2f(xz_ << 16), u2f(xz_ & 0xffff0000u)};
    float xnf[2] = {u2f(xn_ << 16), u2f(xn_ & 0xffff0000u)};
    float den[4];
    den[0] = 1.0f + exp2f(fminf(xrf[0] + aR[0], 14.f));
    den[1] = 1.0f + exp2f(fminf(xrf[1] + aR[1], 14.f));
    den[2] = 1.0f + exp2f(fminf(xzf[0] + aZ[0], 14.f));
    den[3] = 1.0f + exp2f(fminf(xzf[1] + aZ[1], 14.f));
    float inv[4];
    {
      float p0 = den[0], p1 = p0 * den[1], p2 = p1 * den[2];
      float s = __builtin_amdgcn_rcpf(p2 * den[3]);
      inv[3] = p2 * s; s *= den[3];
      inv[2] = p1 * s; s *= den[2];
      inv[1] = p0 * s; s *= den[1];
      inv[0] = s;
    }
    float cden[2];
    cden[0] = 1.0f + exp2f(fminf(fmaf(inv[0], aN[0] + bh_[0], xnf[0]), 14.f));
    cden[1] = 1.0f + exp2f(fminf(fmaf(inv[1], aN[1] + bh_[1], xnf[1]), 14.f));
    float ic[2];
    {
      float p0 = cden[0];
      float s = __builtin_amdgcn_rcpf(p0 * cden[1]);
      ic[1] = p0 * s; s *= cden[1];
      ic[0] = s;
    }
    float o_[2];
#pragma unroll
    for (int r = 0; r < 2; ++r) {
      float ng = fmaf(-2.0f, ic[r], 1.0f);          // tanh
      o_[r] = fmaf(inv[2 + r], h_[r] - ng, ng);     // o = n + z*(h-n)
    }
    float2 o2 = {o_[0], o_[1]};
    *(float2*)yp = o2;
    yp += 256 * 256;
    // carry (mask with next step's reset) + pack to hb16[nxt]
    const float m = rstn ? 0.f : 1.f;
    h_[0] = o_[0] * m; h_[1] = o_[1] * m;
    {
      unsigned hp;
      asm("v_cvt_pk_bf16_f32 %0, %1, %2" : "=v"(hp) : "v"(h_[0]), "v"(h_[1]));
      *(unsigned*)((char*)&hb16[nxt][0] + ((b * 512 + d0 * 2) ^ swb)) = hp;
    }
    // ---- prefetch next step (vmcnt NOT drained at barrier) ----
    if (ts + 1 < Tc) {
      const unsigned short* xn_p = xpp + (long)(ts + 1) * (256 * 768);
      xr_ = *(const unsigned*)(xn_p);
      xz_ = *(const unsigned*)(xn_p + 256);
      xn_ = *(const unsigned*)(xn_p + 512);
      int tg = t0 + ts;
      rstn = (tg + 2 < T_DIM) ? (int)rst8[(tg + 2) * 256 + B0 + b] : 0;
    }
    asm volatile("s_waitcnt lgkmcnt(0)" ::: "memory");
    __builtin_amdgcn_s_barrier();
  }
  float2 hv = {h_[0], h_[1]};
  *(float2*)&hws[(B0 + b) * 256 + d0] = hv;
}

extern "C" void kernel_launch(void* const* d_in, const int* in_sizes, int n_in,
                              void* d_out, int out_size, void* d_ws, size_t ws_size,
                              hipStream_t stream) {
  const float* x    = (const float*)d_in[0];
  const void*  rst  = d_in[1];
  const float* Wi   = (const float*)d_in[2];
  const float* bi   = (const float*)d_in[3];
  const float* Whr  = (const float*)d_in[4];
  const float* Whz  = (const float*)d_in[5];
  const float* Whn  = (const float*)d_in[6];
  const float* bhn  = (const float*)d_in[7];
  float* y = (float*)d_out;

  char* ws = (char*)d_ws;
  unsigned short* Wpk = (unsigned short*)(ws);              // 393216 B
  unsigned short* WiT = (unsigned short*)(ws + 393216);     // 393216 B
  float* hws          = (float*)(ws + 786432);              // 262144 B
  int* flags          = (int*)(ws + 1048576);               // 256 B slot
  unsigned char* rst8 = (unsigned char*)(ws + 1048832);     // 262144 B
  unsigned short* xpb = (unsigned short*)(ws + 1310976);

  const size_t fixed = 1310976;
  int Tc = T_DIM;
  while (Tc > 1 && fixed + (size_t)Tc * B_DIM * 768 * 2 > ws_size) Tc >>= 1;

  hipMemsetAsync(flags, 0, 8, stream);
  detect_resets<<<64, 256, 0, stream>>>((const int*)rst, T_DIM * B_DIM / 4, flags);
  convert_resets<<<256, 256, 0, stream>>>(rst, flags, rst8);
  pack_weights<<<1536, 256, 0, stream>>>(Wi, Whr, Whz, Whn, WiT, Wpk);
  for (int t0 = 0; t0 < T_DIM; t0 += Tc) {
    gemm_xp<<<12 * Tc, 256, 0, stream>>>(x + (long)t0 * B_DIM * D_DIM, WiT, bi, xpb);
    rnn_scan<<<64, 512, 0, stream>>>(xpb, rst8, bhn, Wpk, y, hws, t0, Tc);
  }
}

// Round 6
// 1486.242 us; speedup vs baseline: 4.4757x; 1.0639x over previous
//
#include <hip/hip_runtime.h>

// GRU scan: T=1024, B=256, D=256.
// v6: 128 WGs x 2 batch rows. Per-CU MFMA/step is invariant under batch-split
// (384 MFMA/WG), but gate VALU scales with rows -> 1 elem/thread (3 exp2 + 2 rcp).
// 3-stage fold: DPP shr:4 (tile parity), shr:8 (reg pair), shr:2+cndmask (bit1).
// h-frag LDS reads via base+imm offsets; pointer-increment prefetch.

typedef __attribute__((ext_vector_type(8))) short short8;
typedef __attribute__((ext_vector_type(4))) float f32x4;

#define T_DIM 1024
#define B_DIM 256
#define D_DIM 256
#define SCL_RZ (-1.44269504f)   // -log2(e): sigm(x) = 1/(1+exp2(x*SCL_RZ))
#define SCL_N  (2.88539008f)    // 2*log2(e): tanh(v) = 1-2/(1+exp2(v*SCL_N))

__device__ __forceinline__ unsigned short f2bf(float f) {
  union { float f; unsigned u; } c; c.f = f;
  unsigned r = c.u + 0x7FFFu + ((c.u >> 16) & 1u);  // RNE
  return (unsigned short)(r >> 16);
}
__device__ __forceinline__ float u2f(unsigned u) {
  union { unsigned u; float f; } c; c.u = u;
  return c.f;
}
// lanes q>=4 in each 8 (banks 1,3) take src from lane q-4
__device__ __forceinline__ float dpp_shr4(float own, float src) {
  union { float f; int i; } o, s, r;
  o.f = own; s.f = src;
  r.i = __builtin_amdgcn_update_dpp(o.i, s.i, 0x114, 0xF, 0xA, false);
  return r.f;
}
// lanes q>=8 (banks 2,3) take src from lane q-8
__device__ __forceinline__ float dpp_shr8(float own, float src) {
  union { float f; int i; } o, s, r;
  o.f = own; s.f = src;
  r.i = __builtin_amdgcn_update_dpp(o.i, s.i, 0x118, 0xF, 0xC, false);
  return r.f;
}
// all lanes: value from lane q-2 (lanes 0,1 of each row keep old; unused there)
__device__ __forceinline__ float dpp_shr2(float x) {
  union { float f; int i; } s, r;
  s.f = x;
  r.i = __builtin_amdgcn_update_dpp(s.i, s.i, 0x112, 0xF, 0xF, false);
  return r.f;
}

// resets dtype ambiguous (reference dtype bool). flags[0]=float32, flags[1]=bytes.
__global__ void detect_resets(const int* __restrict__ r, int n, int* __restrict__ flags) {
  int isf = 0, oth = 0;
  for (int i = blockIdx.x * blockDim.x + threadIdx.x; i < n; i += gridDim.x * blockDim.x) {
    int v = r[i];
    if (v == 0x3F800000) isf = 1;
    else if (v != 0 && v != 1) oth = 1;
  }
  if (isf) atomicOr(&flags[0], 1);
  if (oth) atomicOr(&flags[1], 1);
}

__device__ __forceinline__ int read_reset(const void* r, int f0, int f1, int idx) {
  if (f0) return ((const float*)r)[idx] != 0.0f;
  if (f1) return ((const unsigned char*)r)[idx] != 0;
  return ((const int*)r)[idx] != 0;
}

__global__ void convert_resets(const void* __restrict__ rst, const int* __restrict__ flags,
                               unsigned char* __restrict__ rst8) {
  int f0 = flags[0], f1 = flags[1];
  for (int i = blockIdx.x * blockDim.x + threadIdx.x; i < T_DIM * B_DIM;
       i += gridDim.x * blockDim.x)
    rst8[i] = (unsigned char)read_reset(rst, f0, f1, i);
}

// Pack WiT (768x256 bf16, transposed Wi, PRE-SCALED per output col) and Wpk A-frags
// (PRE-SCALED): frag(dt,ks) elem (l,j) = scl(dt)*W[ks*32+(l>>4)*8+j][dt*16+(l&15)].
__global__ void pack_weights(const float* __restrict__ Wi,
                             const float* __restrict__ Whr,
                             const float* __restrict__ Whz,
                             const float* __restrict__ Whn,
                             unsigned short* __restrict__ WiT,
                             unsigned short* __restrict__ Wpk) {
  int gid = blockIdx.x * 256 + threadIdx.x;
  const int NE = 768 * 256;
  if (gid < NE) {
    int n = gid >> 8, k = gid & 255;
    float scl = (n < 512) ? SCL_RZ : SCL_N;
    WiT[gid] = f2bf(Wi[k * 768 + n] * scl);
  } else if (gid < 2 * NE) {
    int g = gid - NE;
    int j = g & 7, l = (g >> 3) & 63, ks = (g >> 9) & 7, nt = g >> 12;
    int k = ks * 32 + (l >> 4) * 8 + j;
    int col = nt * 16 + (l & 15);
    float w;
    if (col < 256)      w = Whr[k * 256 + col] * SCL_RZ;
    else if (col < 512) w = Whz[k * 256 + col - 256] * SCL_RZ;
    else                w = Whn[k * 256 + col - 512] * SCL_N;
    Wpk[g] = f2bf(w);
  }
}

// xp[m][n] = (x@Wi_scaled) + bi[n]*scl(n), output bf16 [T*B][768].
// 1D grid, bijective XCD-affine remap (n-fastest within an XCD's chunk).
__global__ __launch_bounds__(256) void gemm_xp(
    const float* __restrict__ x, const unsigned short* __restrict__ WiT,
    const float* __restrict__ bi, unsigned short* __restrict__ xp) {
  __shared__ __align__(16) unsigned short Al[128 * 64];
  __shared__ __align__(16) unsigned short Bl[128 * 64];
  const int tid = threadIdx.x;
  const int l = tid & 63, wid = tid >> 6;
  const int wm = wid >> 1, wn = wid & 1;
  const int L = blockIdx.x, nwg = gridDim.x;
  const int q = nwg >> 3, r8 = nwg & 7;
  const int c = L & 7, o = L >> 3;
  const int g = c * q + ((c < r8) ? c : r8) + o;
  const int n0 = (g % 6) * 128;
  const long m0 = (long)(g / 6) * 128;
  f32x4 acc[4][4] = {};
  for (int kb = 0; kb < 4; ++kb) {
    const int k0 = kb * 64;
    if (kb) __syncthreads();
#pragma unroll
    for (int i = 0; i < 8; ++i) {
      int fidx = i * 256 + tid;
      int row = fidx >> 4, kf = fidx & 15;
      float4 v = *(const float4*)&x[(m0 + row) * 256 + k0 + kf * 4];
      uint2 p;
      p.x = f2bf(v.x) | ((unsigned)f2bf(v.y) << 16);
      p.y = f2bf(v.z) | ((unsigned)f2bf(v.w) << 16);
      int byte = (row * 128 + kf * 8) ^ ((row & 7) << 4);
      *(uint2*)((char*)Al + byte) = p;
    }
#pragma unroll
    for (int i = 0; i < 4; ++i) {
      int cidx = i * 256 + tid;
      int row = cidx >> 3, kc = cidx & 7;
      short8 v = *(const short8*)&WiT[(n0 + row) * 256 + k0 + kc * 8];
      int byte = (row * 128 + kc * 16) ^ ((row & 7) << 4);
      *(short8*)((char*)Bl + byte) = v;
    }
    __syncthreads();
#pragma unroll
    for (int kk = 0; kk < 2; ++kk) {
      short8 af[4], bfv[4];
#pragma unroll
      for (int t = 0; t < 4; ++t) {
        int m = wm * 64 + t * 16 + (l & 15);
        af[t] = *(const short8*)((char*)Al + ((m * 128 + kk * 64 + (l >> 4) * 16) ^ ((m & 7) << 4)));
        int n = wn * 64 + t * 16 + (l & 15);
        bfv[t] = *(const short8*)((char*)Bl + ((n * 128 + kk * 64 + (l >> 4) * 16) ^ ((n & 7) << 4)));
      }
#pragma unroll
      for (int tm = 0; tm < 4; ++tm)
#pragma unroll
        for (int tn = 0; tn < 4; ++tn)
          acc[tm][tn] = __builtin_amdgcn_mfma_f32_16x16x32_bf16(af[tm], bfv[tn], acc[tm][tn], 0, 0, 0);
    }
  }
#pragma unroll
  for (int tn = 0; tn < 4; ++tn) {
    int n = n0 + wn * 64 + tn * 16 + (l & 15);
    float bscl = bi[n] * ((n < 512) ? SCL_RZ : SCL_N);
#pragma unroll
    for (int tm = 0; tm < 4; ++tm) {
#pragma unroll
      for (int r = 0; r < 4; ++r) {
        long m = m0 + wm * 64 + tm * 16 + (l >> 4) * 4 + r;
        xp[m * 768 + n] = f2bf(acc[tm][tn][r] + bscl);
      }
    }
  }
}

// Recurrent scan v6. 128 WGs x 2 batch rows x 512 threads (8 waves).
// Wave w owns d-cols [w*32, w*32+32) of all gates (6 tiles, 48 frags, reg/AGPR).
// acc[j] = mfma(Wfrag, hfrag): D col = batch (l&15; 0-1 valid), row = grp*4+r.
// 3-stage fold -> lane p owns 1 elem: b = p&1,
// d = w*32 + ((p>>2)&1)*16 + grp*4 + ((p>>3)&1)*2 + ((p>>1)&1).
__global__ __launch_bounds__(512, 2) void rnn_scan(
    const unsigned short* __restrict__ xp, const unsigned char* __restrict__ rst8,
    const float* __restrict__ bhn, const unsigned short* __restrict__ Wpk,
    float* __restrict__ y, float* __restrict__ hws, int t0, int Tc) {
  __shared__ __align__(16) unsigned short hb16[2][2 * 256];  // 2 KB dbuf
  const int tid = threadIdx.x;
  const int l = tid & 63, w = tid >> 6;
  const int p = l & 15, grp = l >> 4;
  const int b = p & 1;
  const int B0 = blockIdx.x * 2;
  const bool odd1 = (p >> 1) & 1;
  const int d0 = w * 32 + ((p >> 2) & 1) * 16 + grp * 4 + ((p >> 3) & 1) * 2 + ((p >> 1) & 1);

  // ---- all 48 weight frags into registers/AGPRs ----
  short8 wreg[48];
#pragma unroll
  for (int t = 0; t < 6; ++t) {
    int dt = (t >> 1) * 16 + w * 2 + (t & 1);
#pragma unroll
    for (int kk = 0; kk < 8; ++kk)
      wreg[t * 8 + kk] = *(const short8*)&Wpk[((dt * 8 + kk) * 64 + l) * 8];
  }
  const float bh = bhn[d0] * SCL_N;

  // ---- init h (1 elem) + hb16[0] ----
  float h = 0.f;
  if (t0 > 0) {
    float hv = hws[(B0 + b) * 256 + d0];
    if (!rst8[t0 * 256 + B0 + b]) h = hv;
  }
  {
    unsigned hp;
    asm("v_cvt_pk_bf16_f32 %0, %1, %2" : "=v"(hp) : "v"(h), "v"(h));
    *(unsigned short*)((char*)&hb16[0][0] + b * 512 + d0 * 2) = (unsigned short)hp;
  }
  __syncthreads();

  // ---- prefetch xp + reset for step 0 (pointer-increment form) ----
  const unsigned short* xpp = xp + ((long)(B0 + b)) * 768 + d0;
  float* yp = y + ((long)t0 * 256 + B0 + b) * 256 + d0;
  unsigned xr_ = *(const unsigned short*)(xpp);
  unsigned xz_ = *(const unsigned short*)(xpp + 256);
  unsigned xn_ = *(const unsigned short*)(xpp + 512);
  xpp += 256 * 768;
  int rstn = (t0 + 1 < T_DIM) ? (int)rst8[(t0 + 1) * 256 + B0 + b] : 0;
  const char* hrd = (const char*)&hb16[0][0] + b * 512 + grp * 16;  // read base (buf0)
  char* hwr = (char*)&hb16[0][0] + b * 512 + d0 * 2;                // write base (buf0)

  for (int ts = 0; ts < Tc; ++ts) {
    const int cur = ts & 1, nxt = cur ^ 1;
    const char* hb = hrd + cur * 1024;
    short8 hfr[3];
#define LD_H(k) (*(const short8*)(hb + (k) * 64))
    hfr[0] = LD_H(0);
    hfr[1] = LD_H(1);
    f32x4 acc[6] = {};
    __builtin_amdgcn_s_setprio(1);
#pragma unroll
    for (int kk = 0; kk < 8; ++kk) {
      if (kk + 2 < 8) hfr[(kk + 2) % 3] = LD_H(kk + 2);
      const int s = kk % 3;
      acc[0] = __builtin_amdgcn_mfma_f32_16x16x32_bf16(wreg[kk],      hfr[s], acc[0], 0, 0, 0);
      acc[1] = __builtin_amdgcn_mfma_f32_16x16x32_bf16(wreg[8 + kk],  hfr[s], acc[1], 0, 0, 0);
      acc[2] = __builtin_amdgcn_mfma_f32_16x16x32_bf16(wreg[16 + kk], hfr[s], acc[2], 0, 0, 0);
      acc[3] = __builtin_amdgcn_mfma_f32_16x16x32_bf16(wreg[24 + kk], hfr[s], acc[3], 0, 0, 0);
      acc[4] = __builtin_amdgcn_mfma_f32_16x16x32_bf16(wreg[32 + kk], hfr[s], acc[4], 0, 0, 0);
      acc[5] = __builtin_amdgcn_mfma_f32_16x16x32_bf16(wreg[40 + kk], hfr[s], acc[5], 0, 0, 0);
    }
    __builtin_amdgcn_s_setprio(0);
#undef LD_H
    // ---- 3-stage fold: 6 tiles x 4 regs -> 1 elem/lane per gate ----
    float aR, aZ, aN;
    {
      float f0, f1, f2, f3, g0, g1;
      f0 = dpp_shr4(acc[0][0], acc[1][0]); f1 = dpp_shr4(acc[0][1], acc[1][1]);
      f2 = dpp_shr4(acc[0][2], acc[1][2]); f3 = dpp_shr4(acc[0][3], acc[1][3]);
      g0 = dpp_shr8(f0, f2); g1 = dpp_shr8(f1, f3);
      aR = odd1 ? dpp_shr2(g1) : g0;
      f0 = dpp_shr4(acc[2][0], acc[3][0]); f1 = dpp_shr4(acc[2][1], acc[3][1]);
      f2 = dpp_shr4(acc[2][2], acc[3][2]); f3 = dpp_shr4(acc[2][3], acc[3][3]);
      g0 = dpp_shr8(f0, f2); g1 = dpp_shr8(f1, f3);
      aZ = odd1 ? dpp_shr2(g1) : g0;
      f0 = dpp_shr4(acc[4][0], acc[5][0]); f1 = dpp_shr4(acc[4][1], acc[5][1]);
      f2 = dpp_shr4(acc[4][2], acc[5][2]); f3 = dpp_shr4(acc[4][3], acc[5][3]);
      g0 = dpp_shr8(f0, f2); g1 = dpp_shr8(f1, f3);
      aN = odd1 ? dpp_shr2(g1) : g0;
    }
    // ---- gates: 1 elem, exp2-direct (3 exp2 + 2 rcp) ----
    float den_r = 1.0f + exp2f(fminf(u2f(xr_ << 16) + aR, 14.f));
    float den_z = 1.0f + exp2f(fminf(u2f(xz_ << 16) + aZ, 14.f));
    float s = __builtin_amdgcn_rcpf(den_r * den_z);
    float rg = den_z * s;   // 1/den_r
    float zg = den_r * s;   // 1/den_z
    float cden = 1.0f + exp2f(fminf(fmaf(rg, aN + bh, u2f(xn_ << 16)), 14.f));
    float ic = __builtin_amdgcn_rcpf(cden);
    float ng = fmaf(-2.0f, ic, 1.0f);            // tanh
    float o = fmaf(zg, h - ng, ng);              // o = n + z*(h-n)
    *yp = o;
    yp += 256 * 256;
    // carry (mask with next step's reset) + pack to hb16[nxt]
    h = rstn ? 0.f : o;
    {
      unsigned hp;
      asm("v_cvt_pk_bf16_f32 %0, %1, %2" : "=v"(hp) : "v"(h), "v"(h));
      *(unsigned short*)(hwr + nxt * 1024) = (unsigned short)hp;
    }
    // ---- prefetch next step (vmcnt NOT drained at barrier) ----
    if (ts + 1 < Tc) {
      xr_ = *(const unsigned short*)(xpp);
      xz_ = *(const unsigned short*)(xpp + 256);
      xn_ = *(const unsigned short*)(xpp + 512);
      xpp += 256 * 768;
      int tg = t0 + ts;
      rstn = (tg + 2 < T_DIM) ? (int)rst8[(tg + 2) * 256 + B0 + b] : 0;
    }
    asm volatile("s_waitcnt lgkmcnt(0)" ::: "memory");
    __builtin_amdgcn_s_barrier();
  }
  hws[(B0 + b) * 256 + d0] = h;
}

extern "C" void kernel_launch(void* const* d_in, const int* in_sizes, int n_in,
                              void* d_out, int out_size, void* d_ws, size_t ws_size,
                              hipStream_t stream) {
  const float* x    = (const float*)d_in[0];
  const void*  rst  = d_in[1];
  const float* Wi   = (const float*)d_in[2];
  const float* bi   = (const float*)d_in[3];
  const float* Whr  = (const float*)d_in[4];
  const float* Whz  = (const float*)d_in[5];
  const float* Whn  = (const float*)d_in[6];
  const float* bhn  = (const float*)d_in[7];
  float* y = (float*)d_out;

  char* ws = (char*)d_ws;
  unsigned short* Wpk = (unsigned short*)(ws);              // 393216 B
  unsigned short* WiT = (unsigned short*)(ws + 393216);     // 393216 B
  float* hws          = (float*)(ws + 786432);              // 262144 B
  int* flags          = (int*)(ws + 1048576);               // 256 B slot
  unsigned char* rst8 = (unsigned char*)(ws + 1048832);     // 262144 B
  unsigned short* xpb = (unsigned short*)(ws + 1310976);

  const size_t fixed = 1310976;
  int Tc = T_DIM;
  while (Tc > 1 && fixed + (size_t)Tc * B_DIM * 768 * 2 > ws_size) Tc >>= 1;

  hipMemsetAsync(flags, 0, 8, stream);
  detect_resets<<<64, 256, 0, stream>>>((const int*)rst, T_DIM * B_DIM / 4, flags);
  convert_resets<<<256, 256, 0, stream>>>(rst, flags, rst8);
  pack_weights<<<1536, 256, 0, stream>>>(Wi, Whr, Whz, Whn, WiT, Wpk);
  for (int t0 = 0; t0 < T_DIM; t0 += Tc) {
    gemm_xp<<<12 * Tc, 256, 0, stream>>>(x + (long)t0 * B_DIM * D_DIM, WiT, bi, xpb);
    rnn_scan<<<128, 512, 0, stream>>>(xpb, rst8, bhn, Wpk, y, hws, t0, Tc);
  }
}

// Round 7
// 1224.529 us; speedup vs baseline: 5.4323x; 1.2137x over previous
//
#include <hip/hip_runtime.h>

// GRU scan: T=1024, B=256, D=256.
// v7: single fused kernel: 128 scan WGs (even blockIdx) + 128 xp-GEMM producer
// WGs (odd blockIdx) running CONCURRENTLY on the other half of the chip.
// Producers publish 64-step rounds via release-atomics; scan spins (rarely).
// Also: h-writeback pair-merged via DPP quad_perm -> one dword write (kills
// the 4-way sub-dword bank conflict of v6).

typedef __attribute__((ext_vector_type(8))) short short8;
typedef __attribute__((ext_vector_type(4))) float f32x4;

#define T_DIM 1024
#define B_DIM 256
#define D_DIM 256
#define SCL_RZ (-1.44269504f)   // -log2(e): sigm(x) = 1/(1+exp2(x*SCL_RZ))
#define SCL_N  (2.88539008f)    // 2*log2(e): tanh(v) = 1-2/(1+exp2(v*SCL_N))

__device__ __forceinline__ unsigned short f2bf(float f) {
  union { float f; unsigned u; } c; c.f = f;
  unsigned r = c.u + 0x7FFFu + ((c.u >> 16) & 1u);  // RNE
  return (unsigned short)(r >> 16);
}
__device__ __forceinline__ float u2f(unsigned u) {
  union { unsigned u; float f; } c; c.u = u;
  return c.f;
}
__device__ __forceinline__ float dpp_shr4(float own, float src) {
  union { float f; int i; } o, s, r;
  o.f = own; s.f = src;
  r.i = __builtin_amdgcn_update_dpp(o.i, s.i, 0x114, 0xF, 0xA, false);
  return r.f;
}
__device__ __forceinline__ float dpp_shr8(float own, float src) {
  union { float f; int i; } o, s, r;
  o.f = own; s.f = src;
  r.i = __builtin_amdgcn_update_dpp(o.i, s.i, 0x118, 0xF, 0xC, false);
  return r.f;
}
__device__ __forceinline__ float dpp_shr2(float x) {
  union { float f; int i; } s, r;
  s.f = x;
  r.i = __builtin_amdgcn_update_dpp(s.i, s.i, 0x112, 0xF, 0xF, false);
  return r.f;
}
// quad_perm [2,3,0,1]: lane q gets value from lane q^2 (pair partner)
__device__ __forceinline__ float dpp_swap2(float x) {
  union { float f; int i; } s, r;
  s.f = x;
  r.i = __builtin_amdgcn_update_dpp(s.i, s.i, 0x4E, 0xF, 0xF, false);
  return r.f;
}

// resets dtype ambiguous (reference dtype bool). flags[0]=float32, flags[1]=bytes.
__global__ void detect_resets(const int* __restrict__ r, int n, int* __restrict__ flags) {
  int isf = 0, oth = 0;
  for (int i = blockIdx.x * blockDim.x + threadIdx.x; i < n; i += gridDim.x * blockDim.x) {
    int v = r[i];
    if (v == 0x3F800000) isf = 1;
    else if (v != 0 && v != 1) oth = 1;
  }
  if (isf) atomicOr(&flags[0], 1);
  if (oth) atomicOr(&flags[1], 1);
}

__device__ __forceinline__ int read_reset(const void* r, int f0, int f1, int idx) {
  if (f0) return ((const float*)r)[idx] != 0.0f;
  if (f1) return ((const unsigned char*)r)[idx] != 0;
  return ((const int*)r)[idx] != 0;
}

__global__ void convert_resets(const void* __restrict__ rst, const int* __restrict__ flags,
                               unsigned char* __restrict__ rst8) {
  int f0 = flags[0], f1 = flags[1];
  for (int i = blockIdx.x * blockDim.x + threadIdx.x; i < T_DIM * B_DIM;
       i += gridDim.x * blockDim.x)
    rst8[i] = (unsigned char)read_reset(rst, f0, f1, i);
}

// Pack WiT (768x256 bf16, transposed Wi, PRE-SCALED per output col) and Wpk A-frags
// (PRE-SCALED): frag(dt,ks) elem (l,j) = scl(dt)*W[ks*32+(l>>4)*8+j][dt*16+(l&15)].
__global__ void pack_weights(const float* __restrict__ Wi,
                             const float* __restrict__ Whr,
                             const float* __restrict__ Whz,
                             const float* __restrict__ Whn,
                             unsigned short* __restrict__ WiT,
                             unsigned short* __restrict__ Wpk) {
  int gid = blockIdx.x * 256 + threadIdx.x;
  const int NE = 768 * 256;
  if (gid < NE) {
    int n = gid >> 8, k = gid & 255;
    float scl = (n < 512) ? SCL_RZ : SCL_N;
    WiT[gid] = f2bf(Wi[k * 768 + n] * scl);
  } else if (gid < 2 * NE) {
    int g = gid - NE;
    int j = g & 7, l = (g >> 3) & 63, ks = (g >> 9) & 7, nt = g >> 12;
    int k = ks * 32 + (l >> 4) * 8 + j;
    int col = nt * 16 + (l & 15);
    float w;
    if (col < 256)      w = Whr[k * 256 + col] * SCL_RZ;
    else if (col < 512) w = Whz[k * 256 + col - 256] * SCL_RZ;
    else                w = Whn[k * 256 + col - 512] * SCL_N;
    Wpk[g] = f2bf(w);
  }
}

// Fused kernel. even blockIdx -> scan WG (2 batch rows); odd -> producer WG.
// Producers compute xp in rounds of 128 m-blocks (64 t-steps), publish rc[r].
__global__ __launch_bounds__(512, 2) void fused(
    const float* __restrict__ x, const unsigned short* __restrict__ WiT,
    const float* __restrict__ bi, unsigned short* __restrict__ xp,
    const unsigned char* __restrict__ rst8, const float* __restrict__ bhn,
    const unsigned short* __restrict__ Wpk, float* __restrict__ y,
    float* __restrict__ hws, int* __restrict__ rc, int t0, int Tc) {
  __shared__ __align__(16) char smem[32768];
  const int tid = threadIdx.x;

  if (blockIdx.x & 1) {
    // ================= producer: xp = x@Wi_scaled + bi_scaled =================
    unsigned short* Al = (unsigned short*)smem;            // 128x64 bf16, swizzled
    unsigned short* Bl = (unsigned short*)(smem + 16384);  // 128x64 bf16, swizzled
    const int pw = blockIdx.x >> 1;
    const int l = tid & 63, wid = tid >> 6;
    const int wm = wid >> 2, wn = wid & 3;   // 2x4 wave grid over 128x128 tile
    const int Mc = Tc * 2;
    const int rounds = (Mc + 127) >> 7;
    for (int r = 0; r < rounds; ++r) {
      const int mb = r * 128 + pw;
      if (mb < Mc) {
        const long m0 = (long)mb * 128;
        for (int nb = 0; nb < 6; ++nb) {
          const int n0 = nb * 128;
          f32x4 acc[4][2] = {};
          for (int kb = 0; kb < 4; ++kb) {
            const int k0 = kb * 64;
            __syncthreads();
#pragma unroll
            for (int i = 0; i < 4; ++i) {  // stage A (x fp32 -> bf16)
              int fidx = i * 512 + tid;
              int row = fidx >> 4, kf = fidx & 15;
              float4 v = *(const float4*)&x[(m0 + row) * 256 + k0 + kf * 4];
              uint2 pk;
              pk.x = f2bf(v.x) | ((unsigned)f2bf(v.y) << 16);
              pk.y = f2bf(v.z) | ((unsigned)f2bf(v.w) << 16);
              int byte = (row * 128 + kf * 8) ^ ((row & 7) << 4);
              *(uint2*)((char*)Al + byte) = pk;
            }
#pragma unroll
            for (int i = 0; i < 2; ++i) {  // stage B (WiT bf16)
              int cidx = i * 512 + tid;
              int row = cidx >> 3, kc = cidx & 7;
              short8 v = *(const short8*)&WiT[(n0 + row) * 256 + k0 + kc * 8];
              int byte = (row * 128 + kc * 16) ^ ((row & 7) << 4);
              *(short8*)((char*)Bl + byte) = v;
            }
            __syncthreads();
#pragma unroll
            for (int kk = 0; kk < 2; ++kk) {
              short8 af[4], bfv[2];
#pragma unroll
              for (int t = 0; t < 4; ++t) {
                int m = wm * 64 + t * 16 + (l & 15);
                af[t] = *(const short8*)((char*)Al + ((m * 128 + kk * 64 + (l >> 4) * 16) ^ ((m & 7) << 4)));
              }
#pragma unroll
              for (int u = 0; u < 2; ++u) {
                int n = wn * 32 + u * 16 + (l & 15);
                bfv[u] = *(const short8*)((char*)Bl + ((n * 128 + kk * 64 + (l >> 4) * 16) ^ ((n & 7) << 4)));
              }
#pragma unroll
              for (int tm = 0; tm < 4; ++tm)
#pragma unroll
                for (int tn = 0; tn < 2; ++tn)
                  acc[tm][tn] = __builtin_amdgcn_mfma_f32_16x16x32_bf16(af[tm], bfv[tn], acc[tm][tn], 0, 0, 0);
            }
          }
#pragma unroll
          for (int tn = 0; tn < 2; ++tn) {
            int n = n0 + wn * 32 + tn * 16 + (l & 15);
            float bscl = bi[n] * ((n < 512) ? SCL_RZ : SCL_N);
#pragma unroll
            for (int tm = 0; tm < 4; ++tm) {
#pragma unroll
              for (int rr = 0; rr < 4; ++rr) {
                long m = m0 + wm * 64 + tm * 16 + (l >> 4) * 4 + rr;
                xp[m * 768 + n] = f2bf(acc[tm][tn][rr] + bscl);
              }
            }
          }
        }
      }
      __syncthreads();  // all waves' stores issued before the flag
      if (tid == 0)
        __hip_atomic_fetch_add(&rc[r], 1, __ATOMIC_RELEASE, __HIP_MEMORY_SCOPE_AGENT);
    }
    return;
  }

  // ================= consumer: recurrent scan (v6 body) =================
  unsigned short* hb16 = (unsigned short*)smem;  // [2][2*256] bf16, 2 KB
  const int l = tid & 63, w = tid >> 6;
  const int p = l & 15, grp = l >> 4;
  const int b = p & 1;
  const int B0 = (blockIdx.x >> 1) * 2;
  const bool odd1 = (p >> 1) & 1;
  const int d0 = w * 32 + ((p >> 2) & 1) * 16 + grp * 4 + ((p >> 3) & 1) * 2 + ((p >> 1) & 1);

  // all 48 weight frags into registers/AGPRs
  short8 wreg[48];
#pragma unroll
  for (int t = 0; t < 6; ++t) {
    int dt = (t >> 1) * 16 + w * 2 + (t & 1);
#pragma unroll
    for (int kk = 0; kk < 8; ++kk)
      wreg[t * 8 + kk] = *(const short8*)&Wpk[((dt * 8 + kk) * 64 + l) * 8];
  }
  const float bh = bhn[d0] * SCL_N;

  // init h (1 elem) + hb16[0]
  float h = 0.f;
  if (t0 > 0) {
    float hv = hws[(B0 + b) * 256 + d0];
    if (!rst8[t0 * 256 + B0 + b]) h = hv;
  }
  {
    unsigned hp;
    asm("v_cvt_pk_bf16_f32 %0, %1, %2" : "=v"(hp) : "v"(h), "v"(h));
    *(unsigned short*)((char*)hb16 + b * 512 + d0 * 2) = (unsigned short)hp;
  }
  __syncthreads();

  // wait for xp round 0, then prefetch step 0
  int done_rounds = 0;
#define WAIT_ROUNDS(rneed)                                                              \
  while (done_rounds <= (rneed)) {                                                     \
    int c_ = __hip_atomic_load(&rc[done_rounds], __ATOMIC_ACQUIRE,                     \
                               __HIP_MEMORY_SCOPE_AGENT);                              \
    if (c_ == 128) ++done_rounds;                                                      \
    else __builtin_amdgcn_s_sleep(8);                                                  \
  }
  WAIT_ROUNDS(0)

  const unsigned short* xpp = xp + ((long)(B0 + b)) * 768 + d0;
  float* yp = y + ((long)t0 * 256 + B0 + b) * 256 + d0;
  unsigned xr_ = *(const unsigned short*)(xpp);
  unsigned xz_ = *(const unsigned short*)(xpp + 256);
  unsigned xn_ = *(const unsigned short*)(xpp + 512);
  xpp += 256 * 768;
  int rstn = (t0 + 1 < T_DIM) ? (int)rst8[(t0 + 1) * 256 + B0 + b] : 0;
  const char* hrd = (const char*)hb16 + b * 512 + grp * 16;         // frag read base
  char* hwr = (char*)hb16 + b * 512 + d0 * 2;                       // merged write base (d0 even lanes)

  for (int ts = 0; ts < Tc; ++ts) {
    const int cur = ts & 1, nxt = cur ^ 1;
    const char* hb = hrd + cur * 1024;
    short8 hfr[3];
#define LD_H(k) (*(const short8*)(hb + (k) * 64))
    hfr[0] = LD_H(0);
    hfr[1] = LD_H(1);
    f32x4 acc[6] = {};
    __builtin_amdgcn_s_setprio(1);
#pragma unroll
    for (int kk = 0; kk < 8; ++kk) {
      if (kk + 2 < 8) hfr[(kk + 2) % 3] = LD_H(kk + 2);
      const int s = kk % 3;
      acc[0] = __builtin_amdgcn_mfma_f32_16x16x32_bf16(wreg[kk],      hfr[s], acc[0], 0, 0, 0);
      acc[1] = __builtin_amdgcn_mfma_f32_16x16x32_bf16(wreg[8 + kk],  hfr[s], acc[1], 0, 0, 0);
      acc[2] = __builtin_amdgcn_mfma_f32_16x16x32_bf16(wreg[16 + kk], hfr[s], acc[2], 0, 0, 0);
      acc[3] = __builtin_amdgcn_mfma_f32_16x16x32_bf16(wreg[24 + kk], hfr[s], acc[3], 0, 0, 0);
      acc[4] = __builtin_amdgcn_mfma_f32_16x16x32_bf16(wreg[32 + kk], hfr[s], acc[4], 0, 0, 0);
      acc[5] = __builtin_amdgcn_mfma_f32_16x16x32_bf16(wreg[40 + kk], hfr[s], acc[5], 0, 0, 0);
    }
    __builtin_amdgcn_s_setprio(0);
#undef LD_H
    // 3-stage fold: 6 tiles x 4 regs -> 1 elem/lane per gate
    float aR, aZ, aN;
    {
      float f0, f1, f2, f3, g0, g1;
      f0 = dpp_shr4(acc[0][0], acc[1][0]); f1 = dpp_shr4(acc[0][1], acc[1][1]);
      f2 = dpp_shr4(acc[0][2], acc[1][2]); f3 = dpp_shr4(acc[0][3], acc[1][3]);
      g0 = dpp_shr8(f0, f2); g1 = dpp_shr8(f1, f3);
      aR = odd1 ? dpp_shr2(g1) : g0;
      f0 = dpp_shr4(acc[2][0], acc[3][0]); f1 = dpp_shr4(acc[2][1], acc[3][1]);
      f2 = dpp_shr4(acc[2][2], acc[3][2]); f3 = dpp_shr4(acc[2][3], acc[3][3]);
      g0 = dpp_shr8(f0, f2); g1 = dpp_shr8(f1, f3);
      aZ = odd1 ? dpp_shr2(g1) : g0;
      f0 = dpp_shr4(acc[4][0], acc[5][0]); f1 = dpp_shr4(acc[4][1], acc[5][1]);
      f2 = dpp_shr4(acc[4][2], acc[5][2]); f3 = dpp_shr4(acc[4][3], acc[5][3]);
      g0 = dpp_shr8(f0, f2); g1 = dpp_shr8(f1, f3);
      aN = odd1 ? dpp_shr2(g1) : g0;
    }
    // gates: 1 elem, exp2-direct (3 exp2 + 2 rcp)
    float den_r = 1.0f + exp2f(fminf(u2f(xr_ << 16) + aR, 14.f));
    float den_z = 1.0f + exp2f(fminf(u2f(xz_ << 16) + aZ, 14.f));
    float s = __builtin_amdgcn_rcpf(den_r * den_z);
    float rg = den_z * s;   // 1/den_r
    float zg = den_r * s;   // 1/den_z
    float cden = 1.0f + exp2f(fminf(fmaf(rg, aN + bh, u2f(xn_ << 16)), 14.f));
    float ic = __builtin_amdgcn_rcpf(cden);
    float ng = fmaf(-2.0f, ic, 1.0f);            // tanh
    float o = fmaf(zg, h - ng, ng);              // o = n + z*(h-n)
    *yp = o;
    yp += 256 * 256;
    // carry (mask with next step's reset); pair-merged dword write to hb16[nxt]
    h = rstn ? 0.f : o;
    {
      float hq = dpp_swap2(h);   // partner lane (p^2) holds d0^1
      if ((p & 2) == 0) {        // even-d0 lanes write (h[d0], h[d0+1]) as one dword
        unsigned hp;
        asm("v_cvt_pk_bf16_f32 %0, %1, %2" : "=v"(hp) : "v"(h), "v"(hq));
        *(unsigned*)(hwr + nxt * 1024) = hp;
      }
    }
    // prefetch next step (vmcnt NOT drained at barrier)
    if (ts + 1 < Tc) {
      WAIT_ROUNDS((2 * ts + 3) >> 7)
      xr_ = *(const unsigned short*)(xpp);
      xz_ = *(const unsigned short*)(xpp + 256);
      xn_ = *(const unsigned short*)(xpp + 512);
      xpp += 256 * 768;
      int tg = t0 + ts;
      rstn = (tg + 2 < T_DIM) ? (int)rst8[(tg + 2) * 256 + B0 + b] : 0;
    }
    asm volatile("s_waitcnt lgkmcnt(0)" ::: "memory");
    __builtin_amdgcn_s_barrier();
  }
#undef WAIT_ROUNDS
  hws[(B0 + b) * 256 + d0] = h;
}

extern "C" void kernel_launch(void* const* d_in, const int* in_sizes, int n_in,
                              void* d_out, int out_size, void* d_ws, size_t ws_size,
                              hipStream_t stream) {
  const float* x    = (const float*)d_in[0];
  const void*  rst  = d_in[1];
  const float* Wi   = (const float*)d_in[2];
  const float* bi   = (const float*)d_in[3];
  const float* Whr  = (const float*)d_in[4];
  const float* Whz  = (const float*)d_in[5];
  const float* Whn  = (const float*)d_in[6];
  const float* bhn  = (const float*)d_in[7];
  float* y = (float*)d_out;

  char* ws = (char*)d_ws;
  unsigned short* Wpk = (unsigned short*)(ws);              // 393216 B
  unsigned short* WiT = (unsigned short*)(ws + 393216);     // 393216 B
  float* hws          = (float*)(ws + 786432);              // 262144 B
  int* flags          = (int*)(ws + 1048576);               // 64 B
  int* rc             = (int*)(ws + 1048640);               // 64 B (16 rounds)
  unsigned char* rst8 = (unsigned char*)(ws + 1048832);     // 262144 B
  unsigned short* xpb = (unsigned short*)(ws + 1310976);

  const size_t fixed = 1310976;
  int Tc = T_DIM;
  while (Tc > 1 && fixed + (size_t)Tc * B_DIM * 768 * 2 > ws_size) Tc >>= 1;

  hipMemsetAsync(flags, 0, 8, stream);
  detect_resets<<<64, 256, 0, stream>>>((const int*)rst, T_DIM * B_DIM / 4, flags);
  convert_resets<<<256, 256, 0, stream>>>(rst, flags, rst8);
  pack_weights<<<1536, 256, 0, stream>>>(Wi, Whr, Whz, Whn, WiT, Wpk);
  for (int t0 = 0; t0 < T_DIM; t0 += Tc) {
    hipMemsetAsync(rc, 0, 64, stream);
    fused<<<256, 512, 0, stream>>>(x + (long)t0 * B_DIM * D_DIM, WiT, bi, xpb,
                                   rst8, bhn, Wpk, y, hws, rc, t0, Tc);
  }
}